// Round 1
// 1068.581 us; speedup vs baseline: 1.4213x; 1.4213x over previous
//
#include <hip/hip_runtime.h>
#include <hip/hip_bf16.h>
#include <math.h>

typedef __hip_bfloat16 bf16;

#define DIMD 128
#define BB 8
#define LL 128
#define TT 512

// esym_gemm tile params
#define BMT 64
#define BKT 32

// Runtime-dtype load of external inputs: bf==1 -> bf16, else f32.
__device__ __forceinline__ float LD(const void* p, long i, int bf) {
    if (bf) return __bfloat162float(((const bf16*)p)[i]);
    return ((const float*)p)[i];
}

// Detect external dtype from emb_W bit patterns + zero the accumulators.
__global__ void init_ws(const unsigned int* __restrict__ embw_raw,
                        float* __restrict__ accum, int* __restrict__ flagp) {
    int t = threadIdx.x;
    if (t < 32) accum[t] = 0.0f;
    if (t == 0) {
        int cnt = 0;
        for (int k = 0; k < 256; ++k) {
            unsigned int b = (embw_raw[k] >> 8) & 0xffu;
            unsigned int e = b & 0x7fu;
            if (e >= 0x38u && e <= 0x3fu) ++cnt;
        }
        *flagp = (cnt > 128) ? 1 : 0;
    }
}

// out[row,d] = sum_k X[row,k] * W[k,d]   (X external dtype, K=54)
__global__ void embed_rows(const void* __restrict__ X, const void* __restrict__ W,
                           float* __restrict__ out, int K, const int* __restrict__ flagp) {
    __shared__ float xrow[DIMD];
    int bf = *flagp;
    int row = blockIdx.x;
    int d = threadIdx.x;
    if (d < K) xrow[d] = LD(X, (long)row * K + d, bf);
    __syncthreads();
    float acc = 0.0f;
    for (int k = 0; k < K; ++k)
        acc = fmaf(xrow[k], LD(W, (long)k * DIMD + d, bf), acc);
    out[(long)row * DIMD + d] = acc;
}

// out[row,d] = sum_k X[row,k] * W[offW + k*128 + d] (+ bias[offB+d])
__global__ void gemm_rows_ws(const float* __restrict__ X, const void* __restrict__ W,
                             long offW, const void* __restrict__ bias, long offB,
                             int hasbias, float* __restrict__ out,
                             const int* __restrict__ flagp) {
    __shared__ float xrow[DIMD];
    int bf = *flagp;
    int row = blockIdx.x;
    int d = threadIdx.x;
    xrow[d] = X[(long)row * DIMD + d];
    __syncthreads();
    float acc = hasbias ? LD(bias, offB + d, bf) : 0.0f;
    for (int k = 0; k < DIMD; ++k)
        acc = fmaf(xrow[k], LD(W, offW + (long)k * DIMD + d, bf), acc);
    out[(long)row * DIMD + d] = acc;
}

// e[b,j,k] = hA_j . h_k + h_j . hA_k  == batched GEMM [hA|h] @ [h|hA]^T, K=256.
// Tiled f32 GEMM: BM=BN=64, BK=32, 256 threads, 4x4 acc per thread.
// LDS panels stored k-major (transposed) so compute reads are ds_read_b128:
//   At[k][row], pad +4 (stride 68 floats, 272B: keeps 16B alignment, 2-way
//   conflict on reads = free; staging transpose-writes are 4-way = minor).
__global__ void esym_gemm(const float* __restrict__ hA, const float* __restrict__ h,
                          float* __restrict__ e, int N) {
    __shared__ float At[BKT][BMT + 4];
    __shared__ float Bt[BKT][BMT + 4];
    int jt = blockIdx.x, kt = blockIdx.y, b = blockIdx.z;
    int t = threadIdx.x;
    const float* hAb = hA + (long)b * N * DIMD;
    const float* hb  = h  + (long)b * N * DIMD;
    int tm = t & 15, tn = t >> 4;          // 16x16 thread grid -> 4x4 outputs each
    int k4 = (t & 7) * 4;                  // staging: float4 col within 32-chunk
    int row0 = t >> 3;                     // staging: rows row0, row0+32
    float acc[4][4];
#pragma unroll
    for (int i = 0; i < 4; ++i)
#pragma unroll
        for (int jj = 0; jj < 4; ++jj) acc[i][jj] = 0.0f;

#pragma unroll
    for (int c = 0; c < 8; ++c) {
        // K=256 concat: first 128 = hA_j . h_k, second 128 = h_j . hA_k
        const float* Ap = (c < 4) ? hAb : hb;
        const float* Bp = (c < 4) ? hb : hAb;
        int ko = (c & 3) * BKT;
        __syncthreads();   // previous chunk's compute done before overwrite
#pragma unroll
        for (int rr = 0; rr < 2; ++rr) {
            int row = row0 + rr * 32;
            // coalesced: 8 lanes cover one row's 32 floats (128B contiguous)
            float4 av = *(const float4*)&Ap[(long)(jt * BMT + row) * DIMD + ko + k4];
            float4 bv = *(const float4*)&Bp[(long)(kt * BMT + row) * DIMD + ko + k4];
            At[k4 + 0][row] = av.x; At[k4 + 1][row] = av.y;
            At[k4 + 2][row] = av.z; At[k4 + 3][row] = av.w;
            Bt[k4 + 0][row] = bv.x; Bt[k4 + 1][row] = bv.y;
            Bt[k4 + 2][row] = bv.z; Bt[k4 + 3][row] = bv.w;
        }
        __syncthreads();
#pragma unroll
        for (int k = 0; k < BKT; ++k) {
            float4 a4 = *(const float4*)&At[k][tm * 4];
            float4 b4 = *(const float4*)&Bt[k][tn * 4];
            float A[4] = {a4.x, a4.y, a4.z, a4.w};
            float Bv[4] = {b4.x, b4.y, b4.z, b4.w};
#pragma unroll
            for (int i = 0; i < 4; ++i)
#pragma unroll
                for (int jj = 0; jj < 4; ++jj)
                    acc[i][jj] = fmaf(A[i], Bv[jj], acc[i][jj]);
        }
    }
    long ebase = ((long)b * N + jt * BMT + tm * 4) * N + kt * BMT + tn * 4;
#pragma unroll
    for (int i = 0; i < 4; ++i) {
        float4 v;
        v.x = acc[i][0]; v.y = acc[i][1]; v.z = acc[i][2]; v.w = acc[i][3];
        *(float4*)&e[ebase + (long)i * N] = v;   // 16 lanes x 16B contiguous
    }
}

// Softmax + hp + gated residual per (b,j). Reads precomputed e row (coalesced).
__global__ void gat_post(float* __restrict__ x, const float* __restrict__ h,
                         const float* __restrict__ e, const void* __restrict__ adj,
                         const void* __restrict__ gW, long offgW,
                         const void* __restrict__ gb, long offgb,
                         int N, const int* __restrict__ flagp) {
    __shared__ float hp[DIMD];
    __shared__ float att[TT], adjrow[TT];
    __shared__ float red[256];
    int bf = *flagp;
    int j = blockIdx.x, b = blockIdx.y, t = threadIdx.x;
    const float* hB = h + (long)b * N * DIMD;
    long adjbase = ((long)b * N + j) * N;
    const float* erow = e + ((long)b * N + j) * N;
    for (int k = t; k < N; k += 256) {
        float a = LD(adj, adjbase + k, bf);
        adjrow[k] = a;
        att[k] = (a > 0.0f) ? erow[k] : -9e15f;
    }
    __syncthreads();
    // softmax over k (denominator over all k, adj applied after -> matches JAX)
    float lm = -3.4e38f;
    for (int k = t; k < N; k += 256) lm = fmaxf(lm, att[k]);
    red[t] = lm; __syncthreads();
    for (int s = 128; s > 0; s >>= 1) { if (t < s) red[t] = fmaxf(red[t], red[t + s]); __syncthreads(); }
    float m = red[0]; __syncthreads();
    float ls = 0.0f;
    for (int k = t; k < N; k += 256) {
        float v = expf(att[k] - m);   // masked: exp(-9e15 - m) -> 0
        ls += v;
        att[k] = v * adjrow[k];
    }
    red[t] = ls; __syncthreads();
    for (int s = 128; s > 0; s >>= 1) { if (t < s) red[t] += red[t + s]; __syncthreads(); }
    float inv = 1.0f / red[0]; __syncthreads();
    // hp[d] = relu(sum_k att[k] * h[k,d]) ; coalesced: lanes span d
    int d = t & (DIMD - 1);
    int kh = t >> 7;
    float acc = 0.0f;
    for (int k = kh; k < N; k += 2)
        acc = fmaf(att[k], hB[(long)k * DIMD + d], acc);
    red[t] = acc; __syncthreads();
    if (t < DIMD) hp[t] = fmaxf((red[t] + red[t + DIMD]) * inv, 0.0f);
    __syncthreads();
    // coeff = sigmoid(concat(x_j, hp) @ gW + gb); x_j = coeff*x_j + (1-coeff)*hp
    float* xrow = x + ((long)b * N + j) * DIMD;
    float gv;
    if (t < DIMD) gv = xrow[t] * LD(gW, offgW + t, bf);
    else          gv = hp[t - DIMD] * LD(gW, offgW + t, bf);
    red[t] = gv; __syncthreads();
    for (int s = 128; s > 0; s >>= 1) { if (t < s) red[t] += red[t + s]; __syncthreads(); }
    float g = red[0] + LD(gb, offgb, bf);
    float coeff = 1.0f / (1.0f + expf(-g));
    __syncthreads();
    if (t < DIMD) xrow[t] = coeff * xrow[t] + (1.0f - coeff) * hp[t];
}

// One block per (b, l). 256 threads, each strides over t in [0,512).
__global__ void pair_energy(const float* __restrict__ ligdc, const float* __restrict__ tgtdc,
                            const float* __restrict__ ligA, const float* __restrict__ tgtA,
                            const void* __restrict__ dcW2, const void* __restrict__ dcb2,
                            const void* __restrict__ AW2, const void* __restrict__ Ab2,
                            const void* __restrict__ lpos, const void* __restrict__ tpos,
                            const void* __restrict__ lrad, const void* __restrict__ trad,
                            const void* __restrict__ lval, const void* __restrict__ tval,
                            const void* __restrict__ ii, float* __restrict__ accum,
                            const int* __restrict__ flagp) {
    int bf = *flagp;
    int l = blockIdx.x, b = blockIdx.y, t = threadIdx.x;
    __shared__ float sdc[DIMD], sA[DIMD], w2dc[DIMD], w2A[DIMD];
    __shared__ float red[256];
    if (t < DIMD) {
        sdc[t] = ligdc[((long)b * LL + l) * DIMD + t];
        sA[t] = ligA[((long)b * LL + l) * DIMD + t];
        w2dc[t] = LD(dcW2, t, bf);
        w2A[t] = LD(AW2, t, bf);
    }
    __syncthreads();
    float lx = LD(lpos, ((long)b * LL + l) * 3 + 0, bf);
    float ly = LD(lpos, ((long)b * LL + l) * 3 + 1, bf);
    float lz = LD(lpos, ((long)b * LL + l) * 3 + 2, bf);
    float lr = LD(lrad, (long)b * LL + l, bf);
    float lv = LD(lval, (long)b * LL + l, bf);
    float cdcb2 = LD(dcb2, 0, bf), cab2 = LD(Ab2, 0, bf);
    long ii0 = ((long)(b * 3 + 0) * LL + l) * TT;
    long ii1 = ((long)(b * 3 + 1) * LL + l) * TT;
    long ii2 = ((long)(b * 3 + 2) * LL + l) * TT;
    float p0 = 0.0f, p1 = 0.0f, p2 = 0.0f, p3 = 0.0f;
    for (int tt = t; tt < TT; tt += 256) {
        float dx = lx - LD(tpos, ((long)b * TT + tt) * 3 + 0, bf);
        float dy = ly - LD(tpos, ((long)b * TT + tt) * 3 + 1, bf);
        float dz = lz - LD(tpos, ((long)b * TT + tt) * 3 + 2, bf);
        float dm = sqrtf(dx * dx + dy * dy + dz * dz + 1e-10f);
        if (dm < 0.5f) dm = 1e10f;
        const float* td = tgtdc + ((long)b * TT + tt) * DIMD;
        const float* ta = tgtA + ((long)b * TT + tt) * DIMD;
        float adc = 0.0f, aA = 0.0f;
        for (int i = 0; i < DIMD; ++i) {
            adc = fmaf(fmaxf(td[i] + sdc[i], 0.0f), w2dc[i], adc);
            aA  = fmaf(fmaxf(ta[i] + sA[i],  0.0f), w2A[i],  aA);
        }
        float dev = tanhf(adc + cdcb2) * 0.2f;
        float vdws = lr + LD(trad, (long)b * TT + tt, bf) + dev;
        float dm0 = (vdws < 1e-4f) ? 1.0f : vdws;
        float ratio = dm0 / dm;
        float r2 = ratio * ratio, r6 = r2 * r2 * r2, r12 = r6 * r6;
        float en = fminf(r12 - 2.0f * r6, 100.0f) * lv * LD(tval, (long)b * TT + tt, bf);
        float As = 1.0f / (1.0f + expf(-(aA + cab2)));
        As = As * (0.0356f - 0.0178f) + 0.0178f;
        p0 = fmaf(As, en, p0);
        float dd = dm - vdws;
        float ramp = fminf(fmaxf(dd * (1.0f / -0.7f), 0.0f), 1.0f);
        p1 = fmaf(ramp, LD(ii, ii0 + tt, bf), p1);
        p2 = fmaf(ramp, LD(ii, ii1 + tt, bf), p2);
        float ramp2 = fminf(fmaxf(-dd + 1.5f, 0.0f), 1.0f);
        p3 = fmaf(ramp2, LD(ii, ii2 + tt, bf), p3);
    }
    for (int e = 0; e < 4; ++e) {
        float v = (e == 0) ? p0 : (e == 1) ? p1 : (e == 2) ? p2 : p3;
        red[t] = v; __syncthreads();
        for (int s = 128; s > 0; s >>= 1) { if (t < s) red[t] += red[t + s]; __syncthreads(); }
        if (t == 0) atomicAdd(&accum[b * 4 + e], red[0]);
        __syncthreads();
    }
}

__global__ void finalize(const float* __restrict__ accum, const void* __restrict__ hb,
                         const void* __restrict__ mc, const void* __restrict__ hyd,
                         const void* __restrict__ rc, const void* __restrict__ rotor,
                         void* __restrict__ out, const int* __restrict__ flagp) {
    int bf = *flagp;
    int t = threadIdx.x;  // 64 threads, use first 32
    if (t >= 32) return;
    int b = t >> 2, e = t & 3;
    float v = accum[t];
    if (e == 1) { float c = LD(hb, 0, bf);  v = -c * c * v; }
    else if (e == 2) { float c = LD(mc, 0, bf);  v = -c * c * v; }
    else if (e == 3) { float c = LD(hyd, 0, bf); v = -c * c * v; }
    float r = LD(rc, 0, bf);
    float den = 1.0f + r * r * LD(rotor, b, bf);
    float res = v / den;
    if (bf) ((bf16*)out)[t] = __float2bfloat16(res);
    else    ((float*)out)[t] = res;
}

extern "C" void kernel_launch(void* const* d_in, const int* in_sizes, int n_in,
                              void* d_out, int out_size, void* d_ws, size_t ws_size,
                              hipStream_t stream) {
    const void* ligand_h = d_in[0];
    const void* target_h = d_in[1];
    const void* ligand_adj = d_in[2];
    const void* target_adj = d_in[3];
    const void* interaction_indice = d_in[4];
    const void* ligand_pos = d_in[5];
    const void* target_pos = d_in[6];
    const void* rotor = d_in[7];
    const void* ligand_vdw = d_in[8];
    const void* target_vdw = d_in[9];
    const void* ligand_valid = d_in[10];
    const void* target_valid = d_in[11];
    const void* emb_W = d_in[12];
    const void* gat_W = d_in[13];
    const void* gat_Wb = d_in[14];
    const void* gat_A = d_in[15];
    const void* gat_gW = d_in[16];
    const void* gat_gb = d_in[17];
    const void* vdwA_W1 = d_in[18];
    const void* vdwA_b1 = d_in[19];
    const void* vdwA_W2 = d_in[20];
    const void* vdwA_b2 = d_in[21];
    const void* dc_W1 = d_in[22];
    const void* dc_b1 = d_in[23];
    const void* dc_W2 = d_in[24];
    const void* dc_b2 = d_in[25];
    const void* hbond_coeff = d_in[26];
    const void* metal_coeff = d_in[27];
    const void* hydrophobic_coeff = d_in[28];
    const void* rotor_coeff = d_in[29];

    float* ws = (float*)d_ws;
    size_t off = 0;
    float* lig_x = ws + off;  off += (size_t)BB * LL * DIMD;
    float* tgt_x = ws + off;  off += (size_t)BB * TT * DIMD;
    float* h_lig = ws + off;  off += (size_t)BB * LL * DIMD;
    float* h_tgt = ws + off;  off += (size_t)BB * TT * DIMD;
    float* hA_lig = ws + off; off += (size_t)BB * LL * DIMD;
    float* hA_tgt = ws + off; off += (size_t)BB * TT * DIMD;
    float* accum = ws + off;  off += 32;
    int* flagp = (int*)(ws + off); off += 2;
    float* e_buf = ws + off;  off += (size_t)BB * TT * TT;  // 8MB; lig reuses it
    // pair-MLP projections reuse h/hA buffers (dead after the GAT loop)
    float* ligdc = h_lig;
    float* tgtdc = h_tgt;
    float* ligA = hA_lig;
    float* tgtA = hA_tgt;

    init_ws<<<1, 64, 0, stream>>>((const unsigned int*)emb_W, accum, flagp);

    // embeddings: x = h @ emb_W
    embed_rows<<<BB * LL, DIMD, 0, stream>>>(ligand_h, emb_W, lig_x, 54, flagp);
    embed_rows<<<BB * TT, DIMD, 0, stream>>>(target_h, emb_W, tgt_x, 54, flagp);

    for (int i = 0; i < 3; ++i) {
        long offW = (long)i * DIMD * DIMD;   // element offsets (dtype-agnostic)
        long offWb = (long)i * DIMD;
        long offgW = (long)i * 2 * DIMD;
        long offgb = i;
        gemm_rows_ws<<<BB * LL, DIMD, 0, stream>>>(lig_x, gat_W, offW, gat_Wb, offWb, 1, h_lig, flagp);
        gemm_rows_ws<<<BB * LL, DIMD, 0, stream>>>(h_lig, gat_A, offW, nullptr, 0, 0, hA_lig, flagp);
        esym_gemm<<<dim3(LL / BMT, LL / BMT, BB), 256, 0, stream>>>(hA_lig, h_lig, e_buf, LL);
        gat_post<<<dim3(LL, BB), 256, 0, stream>>>(lig_x, h_lig, e_buf, ligand_adj,
                                                   gat_gW, offgW, gat_gb, offgb, LL, flagp);
        gemm_rows_ws<<<BB * TT, DIMD, 0, stream>>>(tgt_x, gat_W, offW, gat_Wb, offWb, 1, h_tgt, flagp);
        gemm_rows_ws<<<BB * TT, DIMD, 0, stream>>>(h_tgt, gat_A, offW, nullptr, 0, 0, hA_tgt, flagp);
        esym_gemm<<<dim3(TT / BMT, TT / BMT, BB), 256, 0, stream>>>(hA_tgt, h_tgt, e_buf, TT);
        gat_post<<<dim3(TT, BB), 256, 0, stream>>>(tgt_x, h_tgt, e_buf, target_adj,
                                                   gat_gW, offgW, gat_gb, offgb, TT, flagp);
    }

    // pair-MLP projections (split W1 == concat math; b1 folded into ligand side)
    gemm_rows_ws<<<BB * LL, DIMD, 0, stream>>>(lig_x, dc_W1, 0, dc_b1, 0, 1, ligdc, flagp);
    gemm_rows_ws<<<BB * TT, DIMD, 0, stream>>>(tgt_x, dc_W1, (long)DIMD * DIMD, nullptr, 0, 0, tgtdc, flagp);
    gemm_rows_ws<<<BB * LL, DIMD, 0, stream>>>(lig_x, vdwA_W1, 0, vdwA_b1, 0, 1, ligA, flagp);
    gemm_rows_ws<<<BB * TT, DIMD, 0, stream>>>(tgt_x, vdwA_W1, (long)DIMD * DIMD, nullptr, 0, 0, tgtA, flagp);

    pair_energy<<<dim3(LL, BB), 256, 0, stream>>>(
        ligdc, tgtdc, ligA, tgtA, dc_W2, dc_b2, vdwA_W2, vdwA_b2,
        ligand_pos, target_pos, ligand_vdw, target_vdw,
        ligand_valid, target_valid, interaction_indice, accum, flagp);

    finalize<<<1, 64, 0, stream>>>(accum, hbond_coeff, metal_coeff,
                                   hydrophobic_coeff, rotor_coeff, rotor, d_out, flagp);
}

// Round 2
// 977.531 us; speedup vs baseline: 1.5536x; 1.0931x over previous
//
#include <hip/hip_runtime.h>
#include <hip/hip_bf16.h>
#include <math.h>

typedef __hip_bfloat16 bf16;

#define DIMD 128
#define BB 8
#define LL 128
#define TT 512

// esym_gemm tile params
#define BMT 64
#define BKT 32

// Runtime-dtype load of external inputs: bf==1 -> bf16, else f32.
__device__ __forceinline__ float LD(const void* p, long i, int bf) {
    if (bf) return __bfloat162float(((const bf16*)p)[i]);
    return ((const float*)p)[i];
}

// Detect external dtype from emb_W bit patterns + zero the accumulators.
__global__ void init_ws(const unsigned int* __restrict__ embw_raw,
                        float* __restrict__ accum, int* __restrict__ flagp) {
    int t = threadIdx.x;
    if (t < 32) accum[t] = 0.0f;
    if (t == 0) {
        int cnt = 0;
        for (int k = 0; k < 256; ++k) {
            unsigned int b = (embw_raw[k] >> 8) & 0xffu;
            unsigned int e = b & 0x7fu;
            if (e >= 0x38u && e <= 0x3fu) ++cnt;
        }
        *flagp = (cnt > 128) ? 1 : 0;
    }
}

// out[row,d] = sum_k X[row,k] * W[k,d]   (X external dtype, K=54)
__global__ void embed_rows(const void* __restrict__ X, const void* __restrict__ W,
                           float* __restrict__ out, int K, const int* __restrict__ flagp) {
    __shared__ float xrow[DIMD];
    int bf = *flagp;
    int row = blockIdx.x;
    int d = threadIdx.x;
    if (d < K) xrow[d] = LD(X, (long)row * K + d, bf);
    __syncthreads();
    float acc = 0.0f;
    for (int k = 0; k < K; ++k)
        acc = fmaf(xrow[k], LD(W, (long)k * DIMD + d, bf), acc);
    out[(long)row * DIMD + d] = acc;
}

// out[row,d] = sum_k X[row,k] * W[offW + k*128 + d] (+ bias[offB+d])
// 4 rows per block: one coalesced W load feeds 4 FMAs (was 1:1).
__global__ void gemm_rows_ws(const float* __restrict__ X, const void* __restrict__ W,
                             long offW, const void* __restrict__ bias, long offB,
                             int hasbias, float* __restrict__ out,
                             const int* __restrict__ flagp) {
    __shared__ float xrow[4][DIMD];
    int bf = *flagp;
    long row0 = (long)blockIdx.x * 4;
    int d = threadIdx.x;   // 128 threads
#pragma unroll
    for (int r = 0; r < 4; ++r)
        xrow[r][d] = X[(row0 + r) * DIMD + d];
    __syncthreads();
    float b0 = hasbias ? LD(bias, offB + d, bf) : 0.0f;
    float a0 = b0, a1 = b0, a2 = b0, a3 = b0;
    for (int k = 0; k < DIMD; ++k) {
        float w = LD(W, offW + (long)k * DIMD + d, bf);
        a0 = fmaf(xrow[0][k], w, a0);
        a1 = fmaf(xrow[1][k], w, a1);
        a2 = fmaf(xrow[2][k], w, a2);
        a3 = fmaf(xrow[3][k], w, a3);
    }
    out[(row0 + 0) * DIMD + d] = a0;
    out[(row0 + 1) * DIMD + d] = a1;
    out[(row0 + 2) * DIMD + d] = a2;
    out[(row0 + 3) * DIMD + d] = a3;
}

// e[b,j,k] = hA_j . h_k + h_j . hA_k  == batched GEMM [hA|h] @ [h|hA]^T, K=256.
// Tiled f32 GEMM: BM=BN=64, BK=32, 256 threads, 4x4 acc per thread.
__global__ void esym_gemm(const float* __restrict__ hA, const float* __restrict__ h,
                          float* __restrict__ e, int N) {
    __shared__ float At[BKT][BMT + 4];
    __shared__ float Bt[BKT][BMT + 4];
    int jt = blockIdx.x, kt = blockIdx.y, b = blockIdx.z;
    int t = threadIdx.x;
    const float* hAb = hA + (long)b * N * DIMD;
    const float* hb  = h  + (long)b * N * DIMD;
    int tm = t & 15, tn = t >> 4;          // 16x16 thread grid -> 4x4 outputs each
    int k4 = (t & 7) * 4;                  // staging: float4 col within 32-chunk
    int row0 = t >> 3;                     // staging: rows row0, row0+32
    float acc[4][4];
#pragma unroll
    for (int i = 0; i < 4; ++i)
#pragma unroll
        for (int jj = 0; jj < 4; ++jj) acc[i][jj] = 0.0f;

#pragma unroll
    for (int c = 0; c < 8; ++c) {
        // K=256 concat: first 128 = hA_j . h_k, second 128 = h_j . hA_k
        const float* Ap = (c < 4) ? hAb : hb;
        const float* Bp = (c < 4) ? hb : hAb;
        int ko = (c & 3) * BKT;
        __syncthreads();   // previous chunk's compute done before overwrite
#pragma unroll
        for (int rr = 0; rr < 2; ++rr) {
            int row = row0 + rr * 32;
            float4 av = *(const float4*)&Ap[(long)(jt * BMT + row) * DIMD + ko + k4];
            float4 bv = *(const float4*)&Bp[(long)(kt * BMT + row) * DIMD + ko + k4];
            At[k4 + 0][row] = av.x; At[k4 + 1][row] = av.y;
            At[k4 + 2][row] = av.z; At[k4 + 3][row] = av.w;
            Bt[k4 + 0][row] = bv.x; Bt[k4 + 1][row] = bv.y;
            Bt[k4 + 2][row] = bv.z; Bt[k4 + 3][row] = bv.w;
        }
        __syncthreads();
#pragma unroll
        for (int k = 0; k < BKT; ++k) {
            float4 a4 = *(const float4*)&At[k][tm * 4];
            float4 b4 = *(const float4*)&Bt[k][tn * 4];
            float A[4] = {a4.x, a4.y, a4.z, a4.w};
            float Bv[4] = {b4.x, b4.y, b4.z, b4.w};
#pragma unroll
            for (int i = 0; i < 4; ++i)
#pragma unroll
                for (int jj = 0; jj < 4; ++jj)
                    acc[i][jj] = fmaf(A[i], Bv[jj], acc[i][jj]);
        }
    }
    long ebase = ((long)b * N + jt * BMT + tm * 4) * N + kt * BMT + tn * 4;
#pragma unroll
    for (int i = 0; i < 4; ++i) {
        float4 v;
        v.x = acc[i][0]; v.y = acc[i][1]; v.z = acc[i][2]; v.w = acc[i][3];
        *(float4*)&e[ebase + (long)i * N] = v;
    }
}

// Softmax + hp + gated residual per (b,j). Reads precomputed e row (coalesced).
__global__ void gat_post(float* __restrict__ x, const float* __restrict__ h,
                         const float* __restrict__ e, const void* __restrict__ adj,
                         const void* __restrict__ gW, long offgW,
                         const void* __restrict__ gb, long offgb,
                         int N, const int* __restrict__ flagp) {
    __shared__ float hp[DIMD];
    __shared__ float att[TT], adjrow[TT];
    __shared__ float red[256];
    int bf = *flagp;
    int j = blockIdx.x, b = blockIdx.y, t = threadIdx.x;
    const float* hB = h + (long)b * N * DIMD;
    long adjbase = ((long)b * N + j) * N;
    const float* erow = e + ((long)b * N + j) * N;
    for (int k = t; k < N; k += 256) {
        float a = LD(adj, adjbase + k, bf);
        adjrow[k] = a;
        att[k] = (a > 0.0f) ? erow[k] : -9e15f;
    }
    __syncthreads();
    float lm = -3.4e38f;
    for (int k = t; k < N; k += 256) lm = fmaxf(lm, att[k]);
    red[t] = lm; __syncthreads();
    for (int s = 128; s > 0; s >>= 1) { if (t < s) red[t] = fmaxf(red[t], red[t + s]); __syncthreads(); }
    float m = red[0]; __syncthreads();
    float ls = 0.0f;
    for (int k = t; k < N; k += 256) {
        float v = expf(att[k] - m);
        ls += v;
        att[k] = v * adjrow[k];
    }
    red[t] = ls; __syncthreads();
    for (int s = 128; s > 0; s >>= 1) { if (t < s) red[t] += red[t + s]; __syncthreads(); }
    float inv = 1.0f / red[0]; __syncthreads();
    int d = t & (DIMD - 1);
    int kh = t >> 7;
    float acc = 0.0f;
    for (int k = kh; k < N; k += 2)
        acc = fmaf(att[k], hB[(long)k * DIMD + d], acc);
    red[t] = acc; __syncthreads();
    if (t < DIMD) hp[t] = fmaxf((red[t] + red[t + DIMD]) * inv, 0.0f);
    __syncthreads();
    float* xrow = x + ((long)b * N + j) * DIMD;
    float gv;
    if (t < DIMD) gv = xrow[t] * LD(gW, offgW + t, bf);
    else          gv = hp[t - DIMD] * LD(gW, offgW + t, bf);
    red[t] = gv; __syncthreads();
    for (int s = 128; s > 0; s >>= 1) { if (t < s) red[t] += red[t + s]; __syncthreads(); }
    float g = red[0] + LD(gb, offgb, bf);
    float coeff = 1.0f / (1.0f + expf(-g));
    __syncthreads();
    if (t < DIMD) xrow[t] = coeff * xrow[t] + (1.0f - coeff) * hp[t];
}

// Tiled transpose: in [B*N][128] -> outT [B][128][N]. Coalesced both sides.
__global__ void transpose_to_T(const float* __restrict__ in, float* __restrict__ outT, int N) {
    __shared__ float tile[32][33];
    int b = blockIdx.z;
    int n0 = blockIdx.x * 32;
    int d0 = blockIdx.y * 32;
    int t = threadIdx.x;          // 256 = 32x8
    int tx = t & 31, ty = t >> 5;
    for (int r = ty; r < 32; r += 8)
        tile[r][tx] = in[((long)b * N + n0 + r) * DIMD + d0 + tx];
    __syncthreads();
    for (int r = ty; r < 32; r += 8)
        outT[((long)b * DIMD + d0 + r) * N + n0 + tx] = tile[tx][r];
}

// Pair energies. Block = (b, 2 ligand rows). Lane handles tt = 2t, 2t+1.
// Target projections are TRANSPOSED [B][128][T] -> float2 loads are coalesced.
__global__ void pair_energy(const float* __restrict__ ligdc, const float* __restrict__ tgtdcT,
                            const float* __restrict__ ligA, const float* __restrict__ tgtAT,
                            const void* __restrict__ dcW2, const void* __restrict__ dcb2,
                            const void* __restrict__ AW2, const void* __restrict__ Ab2,
                            const void* __restrict__ lpos, const void* __restrict__ tpos,
                            const void* __restrict__ lrad, const void* __restrict__ trad,
                            const void* __restrict__ lval, const void* __restrict__ tval,
                            const void* __restrict__ ii, float* __restrict__ accum,
                            const int* __restrict__ flagp) {
    int bf = *flagp;
    int l0 = blockIdx.x * 2, b = blockIdx.y, t = threadIdx.x;
    __shared__ __align__(16) float sdc0[DIMD], sdc1[DIMD], sA0[DIMD], sA1[DIMD];
    __shared__ __align__(16) float w2dc[DIMD], w2A[DIMD];
    __shared__ float red[256];
    if (t < DIMD) {
        sdc0[t] = ligdc[((long)b * LL + l0) * DIMD + t];
        sA0[t]  = ligA [((long)b * LL + l0) * DIMD + t];
        w2dc[t] = LD(dcW2, t, bf);
        w2A[t]  = LD(AW2, t, bf);
    } else {
        int u = t - DIMD;
        sdc1[u] = ligdc[((long)b * LL + l0 + 1) * DIMD + u];
        sA1[u]  = ligA [((long)b * LL + l0 + 1) * DIMD + u];
    }
    __syncthreads();
    int tt0 = t * 2;
    const float* tdT = tgtdcT + (long)b * DIMD * TT;
    const float* taT = tgtAT  + (long)b * DIMD * TT;
    // accumulators: adc[lig][ttsub], aA[lig][ttsub]
    float adc00 = 0.0f, adc01 = 0.0f, adc10 = 0.0f, adc11 = 0.0f;
    float aA00 = 0.0f, aA01 = 0.0f, aA10 = 0.0f, aA11 = 0.0f;
    for (int i4 = 0; i4 < DIMD; i4 += 4) {
        float4 wd = *(const float4*)&w2dc[i4];
        float4 wa = *(const float4*)&w2A[i4];
        float4 v0d = *(const float4*)&sdc0[i4];
        float4 v1d = *(const float4*)&sdc1[i4];
        float4 v0a = *(const float4*)&sA0[i4];
        float4 v1a = *(const float4*)&sA1[i4];
        float wdv[4] = {wd.x, wd.y, wd.z, wd.w};
        float wav[4] = {wa.x, wa.y, wa.z, wa.w};
        float s0d[4] = {v0d.x, v0d.y, v0d.z, v0d.w};
        float s1d[4] = {v1d.x, v1d.y, v1d.z, v1d.w};
        float s0a[4] = {v0a.x, v0a.y, v0a.z, v0a.w};
        float s1a[4] = {v1a.x, v1a.y, v1a.z, v1a.w};
#pragma unroll
        for (int j = 0; j < 4; ++j) {
            float2 td = *(const float2*)&tdT[(long)(i4 + j) * TT + tt0];
            float2 ta = *(const float2*)&taT[(long)(i4 + j) * TT + tt0];
            adc00 = fmaf(fmaxf(td.x + s0d[j], 0.0f), wdv[j], adc00);
            adc01 = fmaf(fmaxf(td.y + s0d[j], 0.0f), wdv[j], adc01);
            adc10 = fmaf(fmaxf(td.x + s1d[j], 0.0f), wdv[j], adc10);
            adc11 = fmaf(fmaxf(td.y + s1d[j], 0.0f), wdv[j], adc11);
            aA00 = fmaf(fmaxf(ta.x + s0a[j], 0.0f), wav[j], aA00);
            aA01 = fmaf(fmaxf(ta.y + s0a[j], 0.0f), wav[j], aA01);
            aA10 = fmaf(fmaxf(ta.x + s1a[j], 0.0f), wav[j], aA10);
            aA11 = fmaf(fmaxf(ta.y + s1a[j], 0.0f), wav[j], aA11);
        }
    }
    // per-lig scalars
    float lx0 = LD(lpos, ((long)b * LL + l0) * 3 + 0, bf);
    float ly0 = LD(lpos, ((long)b * LL + l0) * 3 + 1, bf);
    float lz0 = LD(lpos, ((long)b * LL + l0) * 3 + 2, bf);
    float lx1 = LD(lpos, ((long)b * LL + l0 + 1) * 3 + 0, bf);
    float ly1 = LD(lpos, ((long)b * LL + l0 + 1) * 3 + 1, bf);
    float lz1 = LD(lpos, ((long)b * LL + l0 + 1) * 3 + 2, bf);
    float lr0 = LD(lrad, (long)b * LL + l0, bf);
    float lr1 = LD(lrad, (long)b * LL + l0 + 1, bf);
    float lv0 = LD(lval, (long)b * LL + l0, bf);
    float lv1 = LD(lval, (long)b * LL + l0 + 1, bf);
    float cdcb2 = LD(dcb2, 0, bf), cab2 = LD(Ab2, 0, bf);
    long iiA0 = ((long)(b * 3 + 0) * LL + l0) * TT;
    long iiB0 = ((long)(b * 3 + 1) * LL + l0) * TT;
    long iiC0 = ((long)(b * 3 + 2) * LL + l0) * TT;
    long iiA1 = iiA0 + TT, iiB1 = iiB0 + TT, iiC1 = iiC0 + TT;
    float p0 = 0.0f, p1 = 0.0f, p2 = 0.0f, p3 = 0.0f;
#pragma unroll
    for (int jj = 0; jj < 2; ++jj) {
        int tt = tt0 + jj;
        float tx = LD(tpos, ((long)b * TT + tt) * 3 + 0, bf);
        float ty = LD(tpos, ((long)b * TT + tt) * 3 + 1, bf);
        float tz = LD(tpos, ((long)b * TT + tt) * 3 + 2, bf);
        float tr = LD(trad, (long)b * TT + tt, bf);
        float tv = LD(tval, (long)b * TT + tt, bf);
#pragma unroll
        for (int li = 0; li < 2; ++li) {
            float dx = (li ? lx1 : lx0) - tx;
            float dy = (li ? ly1 : ly0) - ty;
            float dz = (li ? lz1 : lz0) - tz;
            float dm = sqrtf(dx * dx + dy * dy + dz * dz + 1e-10f);
            if (dm < 0.5f) dm = 1e10f;
            float adcv = jj ? (li ? adc11 : adc01) : (li ? adc10 : adc00);
            float aAv  = jj ? (li ? aA11  : aA01)  : (li ? aA10  : aA00);
            float dev = tanhf(adcv + cdcb2) * 0.2f;
            float vdws = (li ? lr1 : lr0) + tr + dev;
            float dm0 = (vdws < 1e-4f) ? 1.0f : vdws;
            float ratio = dm0 / dm;
            float r2 = ratio * ratio, r6 = r2 * r2 * r2, r12 = r6 * r6;
            float en = fminf(r12 - 2.0f * r6, 100.0f) * (li ? lv1 : lv0) * tv;
            float As = 1.0f / (1.0f + expf(-(aAv + cab2)));
            As = As * (0.0356f - 0.0178f) + 0.0178f;
            p0 = fmaf(As, en, p0);
            float dd = dm - vdws;
            float ramp = fminf(fmaxf(dd * (1.0f / -0.7f), 0.0f), 1.0f);
            p1 = fmaf(ramp, LD(ii, (li ? iiA1 : iiA0) + tt, bf), p1);
            p2 = fmaf(ramp, LD(ii, (li ? iiB1 : iiB0) + tt, bf), p2);
            float ramp2 = fminf(fmaxf(-dd + 1.5f, 0.0f), 1.0f);
            p3 = fmaf(ramp2, LD(ii, (li ? iiC1 : iiC0) + tt, bf), p3);
        }
    }
    for (int e = 0; e < 4; ++e) {
        float v = (e == 0) ? p0 : (e == 1) ? p1 : (e == 2) ? p2 : p3;
        red[t] = v; __syncthreads();
        for (int s = 128; s > 0; s >>= 1) { if (t < s) red[t] += red[t + s]; __syncthreads(); }
        if (t == 0) atomicAdd(&accum[b * 4 + e], red[0]);
        __syncthreads();
    }
}

__global__ void finalize(const float* __restrict__ accum, const void* __restrict__ hb,
                         const void* __restrict__ mc, const void* __restrict__ hyd,
                         const void* __restrict__ rc, const void* __restrict__ rotor,
                         void* __restrict__ out, const int* __restrict__ flagp) {
    int bf = *flagp;
    int t = threadIdx.x;  // 64 threads, use first 32
    if (t >= 32) return;
    int b = t >> 2, e = t & 3;
    float v = accum[t];
    if (e == 1) { float c = LD(hb, 0, bf);  v = -c * c * v; }
    else if (e == 2) { float c = LD(mc, 0, bf);  v = -c * c * v; }
    else if (e == 3) { float c = LD(hyd, 0, bf); v = -c * c * v; }
    float r = LD(rc, 0, bf);
    float den = 1.0f + r * r * LD(rotor, b, bf);
    float res = v / den;
    if (bf) ((bf16*)out)[t] = __float2bfloat16(res);
    else    ((float*)out)[t] = res;
}

extern "C" void kernel_launch(void* const* d_in, const int* in_sizes, int n_in,
                              void* d_out, int out_size, void* d_ws, size_t ws_size,
                              hipStream_t stream) {
    const void* ligand_h = d_in[0];
    const void* target_h = d_in[1];
    const void* ligand_adj = d_in[2];
    const void* target_adj = d_in[3];
    const void* interaction_indice = d_in[4];
    const void* ligand_pos = d_in[5];
    const void* target_pos = d_in[6];
    const void* rotor = d_in[7];
    const void* ligand_vdw = d_in[8];
    const void* target_vdw = d_in[9];
    const void* ligand_valid = d_in[10];
    const void* target_valid = d_in[11];
    const void* emb_W = d_in[12];
    const void* gat_W = d_in[13];
    const void* gat_Wb = d_in[14];
    const void* gat_A = d_in[15];
    const void* gat_gW = d_in[16];
    const void* gat_gb = d_in[17];
    const void* vdwA_W1 = d_in[18];
    const void* vdwA_b1 = d_in[19];
    const void* vdwA_W2 = d_in[20];
    const void* vdwA_b2 = d_in[21];
    const void* dc_W1 = d_in[22];
    const void* dc_b1 = d_in[23];
    const void* dc_W2 = d_in[24];
    const void* dc_b2 = d_in[25];
    const void* hbond_coeff = d_in[26];
    const void* metal_coeff = d_in[27];
    const void* hydrophobic_coeff = d_in[28];
    const void* rotor_coeff = d_in[29];

    float* ws = (float*)d_ws;
    size_t off = 0;
    float* lig_x = ws + off;  off += (size_t)BB * LL * DIMD;
    float* tgt_x = ws + off;  off += (size_t)BB * TT * DIMD;
    float* h_lig = ws + off;  off += (size_t)BB * LL * DIMD;
    float* h_tgt = ws + off;  off += (size_t)BB * TT * DIMD;
    float* hA_lig = ws + off; off += (size_t)BB * LL * DIMD;
    float* hA_tgt = ws + off; off += (size_t)BB * TT * DIMD;
    float* accum = ws + off;  off += 32;
    int* flagp = (int*)(ws + off); off += 2;
    float* e_buf = ws + off;  off += (size_t)BB * TT * TT;  // 8MB; reused for transposes
    // pair-MLP projections reuse h/hA buffers (dead after the GAT loop)
    float* ligdc = h_lig;
    float* tgtdc = h_tgt;
    float* ligA = hA_lig;
    float* tgtA = hA_tgt;
    // transposed target projections reuse e_buf (dead after the GAT loop)
    float* tgtdcT = e_buf;
    float* tgtAT  = e_buf + (size_t)BB * DIMD * TT;

    init_ws<<<1, 64, 0, stream>>>((const unsigned int*)emb_W, accum, flagp);

    // embeddings: x = h @ emb_W
    embed_rows<<<BB * LL, DIMD, 0, stream>>>(ligand_h, emb_W, lig_x, 54, flagp);
    embed_rows<<<BB * TT, DIMD, 0, stream>>>(target_h, emb_W, tgt_x, 54, flagp);

    for (int i = 0; i < 3; ++i) {
        long offW = (long)i * DIMD * DIMD;   // element offsets (dtype-agnostic)
        long offWb = (long)i * DIMD;
        long offgW = (long)i * 2 * DIMD;
        long offgb = i;
        gemm_rows_ws<<<BB * LL / 4, DIMD, 0, stream>>>(lig_x, gat_W, offW, gat_Wb, offWb, 1, h_lig, flagp);
        gemm_rows_ws<<<BB * LL / 4, DIMD, 0, stream>>>(h_lig, gat_A, offW, nullptr, 0, 0, hA_lig, flagp);
        esym_gemm<<<dim3(LL / BMT, LL / BMT, BB), 256, 0, stream>>>(hA_lig, h_lig, e_buf, LL);
        gat_post<<<dim3(LL, BB), 256, 0, stream>>>(lig_x, h_lig, e_buf, ligand_adj,
                                                   gat_gW, offgW, gat_gb, offgb, LL, flagp);
        gemm_rows_ws<<<BB * TT / 4, DIMD, 0, stream>>>(tgt_x, gat_W, offW, gat_Wb, offWb, 1, h_tgt, flagp);
        gemm_rows_ws<<<BB * TT / 4, DIMD, 0, stream>>>(h_tgt, gat_A, offW, nullptr, 0, 0, hA_tgt, flagp);
        esym_gemm<<<dim3(TT / BMT, TT / BMT, BB), 256, 0, stream>>>(hA_tgt, h_tgt, e_buf, TT);
        gat_post<<<dim3(TT, BB), 256, 0, stream>>>(tgt_x, h_tgt, e_buf, target_adj,
                                                   gat_gW, offgW, gat_gb, offgb, TT, flagp);
    }

    // pair-MLP projections (split W1 == concat math; b1 folded into ligand side)
    gemm_rows_ws<<<BB * LL / 4, DIMD, 0, stream>>>(lig_x, dc_W1, 0, dc_b1, 0, 1, ligdc, flagp);
    gemm_rows_ws<<<BB * TT / 4, DIMD, 0, stream>>>(tgt_x, dc_W1, (long)DIMD * DIMD, nullptr, 0, 0, tgtdc, flagp);
    gemm_rows_ws<<<BB * LL / 4, DIMD, 0, stream>>>(lig_x, vdwA_W1, 0, vdwA_b1, 0, 1, ligA, flagp);
    gemm_rows_ws<<<BB * TT / 4, DIMD, 0, stream>>>(tgt_x, vdwA_W1, (long)DIMD * DIMD, nullptr, 0, 0, tgtA, flagp);

    // transpose target projections for coalesced pair_energy reads
    transpose_to_T<<<dim3(TT / 32, DIMD / 32, BB), 256, 0, stream>>>(tgtdc, tgtdcT, TT);
    transpose_to_T<<<dim3(TT / 32, DIMD / 32, BB), 256, 0, stream>>>(tgtA, tgtAT, TT);

    pair_energy<<<dim3(LL / 2, BB), 256, 0, stream>>>(
        ligdc, tgtdcT, ligA, tgtAT, dc_W2, dc_b2, vdwA_W2, vdwA_b2,
        ligand_pos, target_pos, ligand_vdw, target_vdw,
        ligand_valid, target_valid, interaction_indice, accum, flagp);

    finalize<<<1, 64, 0, stream>>>(accum, hbond_coeff, metal_coeff,
                                   hydrophobic_coeff, rotor_coeff, rotor, d_out, flagp);
}

// Round 3
// 609.404 us; speedup vs baseline: 2.4921x; 1.6041x over previous
//
#include <hip/hip_runtime.h>
#include <hip/hip_bf16.h>
#include <math.h>

typedef __hip_bfloat16 bf16;

#define DIMD 128
#define BB 8
#define LL 128
#define TT 512

// esym_gemm tile params
#define BMT 64
#define BKT 32

// Runtime-dtype load of external inputs: bf==1 -> bf16, else f32.
__device__ __forceinline__ float LD(const void* p, long i, int bf) {
    if (bf) return __bfloat162float(((const bf16*)p)[i]);
    return ((const float*)p)[i];
}

// Detect external dtype from emb_W bit patterns + zero the accumulators.
__global__ void init_ws(const unsigned int* __restrict__ embw_raw,
                        float* __restrict__ accum, int* __restrict__ flagp) {
    int t = threadIdx.x;
    if (t < 32) accum[t] = 0.0f;
    if (t == 0) {
        int cnt = 0;
        for (int k = 0; k < 256; ++k) {
            unsigned int b = (embw_raw[k] >> 8) & 0xffu;
            unsigned int e = b & 0x7fu;
            if (e >= 0x38u && e <= 0x3fu) ++cnt;
        }
        *flagp = (cnt > 128) ? 1 : 0;
    }
}

// out[row,d] = sum_k X[row,k] * W[k,d]   (X external dtype, K=54)
__global__ void embed_rows(const void* __restrict__ X, const void* __restrict__ W,
                           float* __restrict__ out, int K, const int* __restrict__ flagp) {
    __shared__ float xrow[DIMD];
    int bf = *flagp;
    int row = blockIdx.x;
    int d = threadIdx.x;
    if (d < K) xrow[d] = LD(X, (long)row * K + d, bf);
    __syncthreads();
    float acc = 0.0f;
    for (int k = 0; k < K; ++k)
        acc = fmaf(xrow[k], LD(W, (long)k * DIMD + d, bf), acc);
    out[(long)row * DIMD + d] = acc;
}

// out[row,d] = sum_k X[row,k] * W[offW + k*128 + d] (+ bias[offB+d])
// 4 rows per block: one coalesced W load feeds 4 FMAs.
__global__ void gemm_rows_ws(const float* __restrict__ X, const void* __restrict__ W,
                             long offW, const void* __restrict__ bias, long offB,
                             int hasbias, float* __restrict__ out,
                             const int* __restrict__ flagp) {
    __shared__ float xrow[4][DIMD];
    int bf = *flagp;
    long row0 = (long)blockIdx.x * 4;
    int d = threadIdx.x;   // 128 threads
#pragma unroll
    for (int r = 0; r < 4; ++r)
        xrow[r][d] = X[(row0 + r) * DIMD + d];
    __syncthreads();
    float b0 = hasbias ? LD(bias, offB + d, bf) : 0.0f;
    float a0 = b0, a1 = b0, a2 = b0, a3 = b0;
    for (int k = 0; k < DIMD; ++k) {
        float w = LD(W, offW + (long)k * DIMD + d, bf);
        a0 = fmaf(xrow[0][k], w, a0);
        a1 = fmaf(xrow[1][k], w, a1);
        a2 = fmaf(xrow[2][k], w, a2);
        a3 = fmaf(xrow[3][k], w, a3);
    }
    out[(row0 + 0) * DIMD + d] = a0;
    out[(row0 + 1) * DIMD + d] = a1;
    out[(row0 + 2) * DIMD + d] = a2;
    out[(row0 + 3) * DIMD + d] = a3;
}

// e[b,j,k] = hA_j . h_k + h_j . hA_k  == batched GEMM [hA|h] @ [h|hA]^T, K=256.
__global__ void esym_gemm(const float* __restrict__ hA, const float* __restrict__ h,
                          float* __restrict__ e, int N) {
    __shared__ float At[BKT][BMT + 4];
    __shared__ float Bt[BKT][BMT + 4];
    int jt = blockIdx.x, kt = blockIdx.y, b = blockIdx.z;
    int t = threadIdx.x;
    const float* hAb = hA + (long)b * N * DIMD;
    const float* hb  = h  + (long)b * N * DIMD;
    int tm = t & 15, tn = t >> 4;
    int k4 = (t & 7) * 4;
    int row0 = t >> 3;
    float acc[4][4];
#pragma unroll
    for (int i = 0; i < 4; ++i)
#pragma unroll
        for (int jj = 0; jj < 4; ++jj) acc[i][jj] = 0.0f;

#pragma unroll
    for (int c = 0; c < 8; ++c) {
        const float* Ap = (c < 4) ? hAb : hb;
        const float* Bp = (c < 4) ? hb : hAb;
        int ko = (c & 3) * BKT;
        __syncthreads();
#pragma unroll
        for (int rr = 0; rr < 2; ++rr) {
            int row = row0 + rr * 32;
            float4 av = *(const float4*)&Ap[(long)(jt * BMT + row) * DIMD + ko + k4];
            float4 bv = *(const float4*)&Bp[(long)(kt * BMT + row) * DIMD + ko + k4];
            At[k4 + 0][row] = av.x; At[k4 + 1][row] = av.y;
            At[k4 + 2][row] = av.z; At[k4 + 3][row] = av.w;
            Bt[k4 + 0][row] = bv.x; Bt[k4 + 1][row] = bv.y;
            Bt[k4 + 2][row] = bv.z; Bt[k4 + 3][row] = bv.w;
        }
        __syncthreads();
#pragma unroll
        for (int k = 0; k < BKT; ++k) {
            float4 a4 = *(const float4*)&At[k][tm * 4];
            float4 b4 = *(const float4*)&Bt[k][tn * 4];
            float A[4] = {a4.x, a4.y, a4.z, a4.w};
            float Bv[4] = {b4.x, b4.y, b4.z, b4.w};
#pragma unroll
            for (int i = 0; i < 4; ++i)
#pragma unroll
                for (int jj = 0; jj < 4; ++jj)
                    acc[i][jj] = fmaf(A[i], Bv[jj], acc[i][jj]);
        }
    }
    long ebase = ((long)b * N + jt * BMT + tm * 4) * N + kt * BMT + tn * 4;
#pragma unroll
    for (int i = 0; i < 4; ++i) {
        float4 v;
        v.x = acc[i][0]; v.y = acc[i][1]; v.z = acc[i][2]; v.w = acc[i][3];
        *(float4*)&e[ebase + (long)i * N] = v;
    }
}

// att row softmax, one WAVE per row (no barriers). In-place on e.
// att[k] = (exp(masked e[k] - m) / sum) * adj[k]   (sum over all k incl. masked->0)
template<int CNT>
__global__ void att_softmax(float* __restrict__ e, const void* __restrict__ adj,
                            int N, const int* __restrict__ flagp) {
    int bf = *flagp;
    int b = blockIdx.y;
    int j = blockIdx.x * 4 + (threadIdx.x >> 6);
    int lane = threadIdx.x & 63;
    float* erow = e + ((long)b * N + j) * N;
    long adjbase = ((long)b * N + j) * N;
    float vals[CNT], av[CNT];
    float m = -3.4e38f;
#pragma unroll
    for (int i = 0; i < CNT; ++i) {
        int k = lane + i * 64;
        float a = LD(adj, adjbase + k, bf);
        float v = (a > 0.0f) ? erow[k] : -9e15f;
        av[i] = a; vals[i] = v;
        m = fmaxf(m, v);
    }
#pragma unroll
    for (int s = 32; s > 0; s >>= 1) m = fmaxf(m, __shfl_xor(m, s));
    float sum = 0.0f;
#pragma unroll
    for (int i = 0; i < CNT; ++i) { vals[i] = expf(vals[i] - m); sum += vals[i]; }
#pragma unroll
    for (int s = 32; s > 0; s >>= 1) sum += __shfl_xor(sum, s);
    float inv = 1.0f / sum;
#pragma unroll
    for (int i = 0; i < CNT; ++i)
        erow[lane + i * 64] = vals[i] * av[i] * inv;
}

// Partial hp GEMM: part[b][j][d] += over k-chunk of att[b][j][k] * h[b][k][d]
// BM=32, BN=128 (full D), BK=32, 256 threads, 4x4 acc, split-K=2 via blockIdx.y.
__global__ void hp_gemm(const float* __restrict__ att, const float* __restrict__ h,
                        float* __restrict__ part0, float* __restrict__ part1, int N) {
    __shared__ float At[32][36];    // [k][row], pad to 36
    __shared__ float Ht[32][DIMD];  // [k][d]
    int jt = blockIdx.x, kc = blockIdx.y, b = blockIdx.z;
    int t = threadIdx.x;
    const float* attb = att + (long)b * N * N;
    const float* hb = h + (long)b * N * DIMD;
    int tm = t & 7, tn = t >> 3;    // rows tm*4.., cols tn*4..
    float acc[4][4] = {};
    int kchunk = N / 2;
    int kbeg = kc * kchunk;
    int ar = t >> 3;                // att stage: tile row 0..31
    int ac4 = (t & 7) * 4;          // att stage: k within 32-chunk
    int hk = t >> 5;                // h stage: k row base 0..7 (step 8)
    int hc4 = (t & 31) * 4;         // h stage: col
    for (int k0 = kbeg; k0 < kbeg + kchunk; k0 += 32) {
        __syncthreads();
        float4 av = *(const float4*)&attb[(long)(jt * 32 + ar) * N + k0 + ac4];
        At[ac4 + 0][ar] = av.x; At[ac4 + 1][ar] = av.y;
        At[ac4 + 2][ar] = av.z; At[ac4 + 3][ar] = av.w;
#pragma unroll
        for (int p = 0; p < 4; ++p)
            *(float4*)&Ht[hk + p * 8][hc4] = *(const float4*)&hb[(long)(k0 + hk + p * 8) * DIMD + hc4];
        __syncthreads();
#pragma unroll
        for (int k = 0; k < 32; ++k) {
            float4 a4 = *(const float4*)&At[k][tm * 4];
            float4 h4 = *(const float4*)&Ht[k][tn * 4];
            float A[4] = {a4.x, a4.y, a4.z, a4.w};
            float H[4] = {h4.x, h4.y, h4.z, h4.w};
#pragma unroll
            for (int i = 0; i < 4; ++i)
#pragma unroll
                for (int jj = 0; jj < 4; ++jj)
                    acc[i][jj] = fmaf(A[i], H[jj], acc[i][jj]);
        }
    }
    float* outp = (kc == 0) ? part0 : part1;
    long obase = ((long)b * N + jt * 32 + tm * 4) * DIMD + tn * 4;
#pragma unroll
    for (int i = 0; i < 4; ++i) {
        float4 v; v.x = acc[i][0]; v.y = acc[i][1]; v.z = acc[i][2]; v.w = acc[i][3];
        *(float4*)&outp[obase + (long)i * DIMD] = v;
    }
}

// Gate: hp = relu(part0+part1); coeff = sigmoid(concat(x,hp)@gW+gb); x updated.
// One WAVE per row, no barriers.
__global__ void gat_gate(float* __restrict__ x, const float* __restrict__ part0,
                         const float* __restrict__ part1,
                         const void* __restrict__ gW, long offgW,
                         const void* __restrict__ gb, long offgb,
                         int N, const int* __restrict__ flagp) {
    int bf = *flagp;
    int b = blockIdx.y;
    int j = blockIdx.x * 4 + (threadIdx.x >> 6);
    int lane = threadIdx.x & 63;
    long rbase = ((long)b * N + j) * DIMD;
    float* xrow = x + rbase;
    float hp0 = fmaxf(part0[rbase + lane] + part1[rbase + lane], 0.0f);
    float hp1 = fmaxf(part0[rbase + lane + 64] + part1[rbase + lane + 64], 0.0f);
    float x0 = xrow[lane], x1 = xrow[lane + 64];
    float g = x0 * LD(gW, offgW + lane, bf) + x1 * LD(gW, offgW + lane + 64, bf)
            + hp0 * LD(gW, offgW + DIMD + lane, bf) + hp1 * LD(gW, offgW + DIMD + lane + 64, bf);
#pragma unroll
    for (int s = 32; s > 0; s >>= 1) g += __shfl_xor(g, s);
    g += LD(gb, offgb, bf);
    float coeff = 1.0f / (1.0f + expf(-g));
    xrow[lane] = coeff * x0 + (1.0f - coeff) * hp0;
    xrow[lane + 64] = coeff * x1 + (1.0f - coeff) * hp1;
}

// Tiled transpose: in [B*N][128] -> outT [B][128][N]. Coalesced both sides.
__global__ void transpose_to_T(const float* __restrict__ in, float* __restrict__ outT, int N) {
    __shared__ float tile[32][33];
    int b = blockIdx.z;
    int n0 = blockIdx.x * 32;
    int d0 = blockIdx.y * 32;
    int t = threadIdx.x;          // 256 = 32x8
    int tx = t & 31, ty = t >> 5;
    for (int r = ty; r < 32; r += 8)
        tile[r][tx] = in[((long)b * N + n0 + r) * DIMD + d0 + tx];
    __syncthreads();
    for (int r = ty; r < 32; r += 8)
        outT[((long)b * DIMD + d0 + r) * N + n0 + tx] = tile[tx][r];
}

// Pair energies. Block = (b, 2 ligand rows). Lane handles tt = 2t, 2t+1.
__global__ void pair_energy(const float* __restrict__ ligdc, const float* __restrict__ tgtdcT,
                            const float* __restrict__ ligA, const float* __restrict__ tgtAT,
                            const void* __restrict__ dcW2, const void* __restrict__ dcb2,
                            const void* __restrict__ AW2, const void* __restrict__ Ab2,
                            const void* __restrict__ lpos, const void* __restrict__ tpos,
                            const void* __restrict__ lrad, const void* __restrict__ trad,
                            const void* __restrict__ lval, const void* __restrict__ tval,
                            const void* __restrict__ ii, float* __restrict__ accum,
                            const int* __restrict__ flagp) {
    int bf = *flagp;
    int l0 = blockIdx.x * 2, b = blockIdx.y, t = threadIdx.x;
    __shared__ __align__(16) float sdc0[DIMD], sdc1[DIMD], sA0[DIMD], sA1[DIMD];
    __shared__ __align__(16) float w2dc[DIMD], w2A[DIMD];
    __shared__ float red[256];
    if (t < DIMD) {
        sdc0[t] = ligdc[((long)b * LL + l0) * DIMD + t];
        sA0[t]  = ligA [((long)b * LL + l0) * DIMD + t];
        w2dc[t] = LD(dcW2, t, bf);
        w2A[t]  = LD(AW2, t, bf);
    } else {
        int u = t - DIMD;
        sdc1[u] = ligdc[((long)b * LL + l0 + 1) * DIMD + u];
        sA1[u]  = ligA [((long)b * LL + l0 + 1) * DIMD + u];
    }
    __syncthreads();
    int tt0 = t * 2;
    const float* tdT = tgtdcT + (long)b * DIMD * TT;
    const float* taT = tgtAT  + (long)b * DIMD * TT;
    float adc00 = 0.0f, adc01 = 0.0f, adc10 = 0.0f, adc11 = 0.0f;
    float aA00 = 0.0f, aA01 = 0.0f, aA10 = 0.0f, aA11 = 0.0f;
    for (int i4 = 0; i4 < DIMD; i4 += 4) {
        float4 wd = *(const float4*)&w2dc[i4];
        float4 wa = *(const float4*)&w2A[i4];
        float4 v0d = *(const float4*)&sdc0[i4];
        float4 v1d = *(const float4*)&sdc1[i4];
        float4 v0a = *(const float4*)&sA0[i4];
        float4 v1a = *(const float4*)&sA1[i4];
        float wdv[4] = {wd.x, wd.y, wd.z, wd.w};
        float wav[4] = {wa.x, wa.y, wa.z, wa.w};
        float s0d[4] = {v0d.x, v0d.y, v0d.z, v0d.w};
        float s1d[4] = {v1d.x, v1d.y, v1d.z, v1d.w};
        float s0a[4] = {v0a.x, v0a.y, v0a.z, v0a.w};
        float s1a[4] = {v1a.x, v1a.y, v1a.z, v1a.w};
#pragma unroll
        for (int j = 0; j < 4; ++j) {
            float2 td = *(const float2*)&tdT[(long)(i4 + j) * TT + tt0];
            float2 ta = *(const float2*)&taT[(long)(i4 + j) * TT + tt0];
            adc00 = fmaf(fmaxf(td.x + s0d[j], 0.0f), wdv[j], adc00);
            adc01 = fmaf(fmaxf(td.y + s0d[j], 0.0f), wdv[j], adc01);
            adc10 = fmaf(fmaxf(td.x + s1d[j], 0.0f), wdv[j], adc10);
            adc11 = fmaf(fmaxf(td.y + s1d[j], 0.0f), wdv[j], adc11);
            aA00 = fmaf(fmaxf(ta.x + s0a[j], 0.0f), wav[j], aA00);
            aA01 = fmaf(fmaxf(ta.y + s0a[j], 0.0f), wav[j], aA01);
            aA10 = fmaf(fmaxf(ta.x + s1a[j], 0.0f), wav[j], aA10);
            aA11 = fmaf(fmaxf(ta.y + s1a[j], 0.0f), wav[j], aA11);
        }
    }
    float lx0 = LD(lpos, ((long)b * LL + l0) * 3 + 0, bf);
    float ly0 = LD(lpos, ((long)b * LL + l0) * 3 + 1, bf);
    float lz0 = LD(lpos, ((long)b * LL + l0) * 3 + 2, bf);
    float lx1 = LD(lpos, ((long)b * LL + l0 + 1) * 3 + 0, bf);
    float ly1 = LD(lpos, ((long)b * LL + l0 + 1) * 3 + 1, bf);
    float lz1 = LD(lpos, ((long)b * LL + l0 + 1) * 3 + 2, bf);
    float lr0 = LD(lrad, (long)b * LL + l0, bf);
    float lr1 = LD(lrad, (long)b * LL + l0 + 1, bf);
    float lv0 = LD(lval, (long)b * LL + l0, bf);
    float lv1 = LD(lval, (long)b * LL + l0 + 1, bf);
    float cdcb2 = LD(dcb2, 0, bf), cab2 = LD(Ab2, 0, bf);
    long iiA0 = ((long)(b * 3 + 0) * LL + l0) * TT;
    long iiB0 = ((long)(b * 3 + 1) * LL + l0) * TT;
    long iiC0 = ((long)(b * 3 + 2) * LL + l0) * TT;
    long iiA1 = iiA0 + TT, iiB1 = iiB0 + TT, iiC1 = iiC0 + TT;
    float p0 = 0.0f, p1 = 0.0f, p2 = 0.0f, p3 = 0.0f;
#pragma unroll
    for (int jj = 0; jj < 2; ++jj) {
        int tt = tt0 + jj;
        float tx = LD(tpos, ((long)b * TT + tt) * 3 + 0, bf);
        float ty = LD(tpos, ((long)b * TT + tt) * 3 + 1, bf);
        float tz = LD(tpos, ((long)b * TT + tt) * 3 + 2, bf);
        float tr = LD(trad, (long)b * TT + tt, bf);
        float tv = LD(tval, (long)b * TT + tt, bf);
#pragma unroll
        for (int li = 0; li < 2; ++li) {
            float dx = (li ? lx1 : lx0) - tx;
            float dy = (li ? ly1 : ly0) - ty;
            float dz = (li ? lz1 : lz0) - tz;
            float dm = sqrtf(dx * dx + dy * dy + dz * dz + 1e-10f);
            if (dm < 0.5f) dm = 1e10f;
            float adcv = jj ? (li ? adc11 : adc01) : (li ? adc10 : adc00);
            float aAv  = jj ? (li ? aA11  : aA01)  : (li ? aA10  : aA00);
            float dev = tanhf(adcv + cdcb2) * 0.2f;
            float vdws = (li ? lr1 : lr0) + tr + dev;
            float dm0 = (vdws < 1e-4f) ? 1.0f : vdws;
            float ratio = dm0 / dm;
            float r2 = ratio * ratio, r6 = r2 * r2 * r2, r12 = r6 * r6;
            float en = fminf(r12 - 2.0f * r6, 100.0f) * (li ? lv1 : lv0) * tv;
            float As = 1.0f / (1.0f + expf(-(aAv + cab2)));
            As = As * (0.0356f - 0.0178f) + 0.0178f;
            p0 = fmaf(As, en, p0);
            float dd = dm - vdws;
            float ramp = fminf(fmaxf(dd * (1.0f / -0.7f), 0.0f), 1.0f);
            p1 = fmaf(ramp, LD(ii, (li ? iiA1 : iiA0) + tt, bf), p1);
            p2 = fmaf(ramp, LD(ii, (li ? iiB1 : iiB0) + tt, bf), p2);
            float ramp2 = fminf(fmaxf(-dd + 1.5f, 0.0f), 1.0f);
            p3 = fmaf(ramp2, LD(ii, (li ? iiC1 : iiC0) + tt, bf), p3);
        }
    }
    for (int e = 0; e < 4; ++e) {
        float v = (e == 0) ? p0 : (e == 1) ? p1 : (e == 2) ? p2 : p3;
        red[t] = v; __syncthreads();
        for (int s = 128; s > 0; s >>= 1) { if (t < s) red[t] += red[t + s]; __syncthreads(); }
        if (t == 0) atomicAdd(&accum[b * 4 + e], red[0]);
        __syncthreads();
    }
}

__global__ void finalize(const float* __restrict__ accum, const void* __restrict__ hb,
                         const void* __restrict__ mc, const void* __restrict__ hyd,
                         const void* __restrict__ rc, const void* __restrict__ rotor,
                         void* __restrict__ out, const int* __restrict__ flagp) {
    int bf = *flagp;
    int t = threadIdx.x;  // 64 threads, use first 32
    if (t >= 32) return;
    int b = t >> 2, e = t & 3;
    float v = accum[t];
    if (e == 1) { float c = LD(hb, 0, bf);  v = -c * c * v; }
    else if (e == 2) { float c = LD(mc, 0, bf);  v = -c * c * v; }
    else if (e == 3) { float c = LD(hyd, 0, bf); v = -c * c * v; }
    float r = LD(rc, 0, bf);
    float den = 1.0f + r * r * LD(rotor, b, bf);
    float res = v / den;
    if (bf) ((bf16*)out)[t] = __float2bfloat16(res);
    else    ((float*)out)[t] = res;
}

extern "C" void kernel_launch(void* const* d_in, const int* in_sizes, int n_in,
                              void* d_out, int out_size, void* d_ws, size_t ws_size,
                              hipStream_t stream) {
    const void* ligand_h = d_in[0];
    const void* target_h = d_in[1];
    const void* ligand_adj = d_in[2];
    const void* target_adj = d_in[3];
    const void* interaction_indice = d_in[4];
    const void* ligand_pos = d_in[5];
    const void* target_pos = d_in[6];
    const void* rotor = d_in[7];
    const void* ligand_vdw = d_in[8];
    const void* target_vdw = d_in[9];
    const void* ligand_valid = d_in[10];
    const void* target_valid = d_in[11];
    const void* emb_W = d_in[12];
    const void* gat_W = d_in[13];
    const void* gat_Wb = d_in[14];
    const void* gat_A = d_in[15];
    const void* gat_gW = d_in[16];
    const void* gat_gb = d_in[17];
    const void* vdwA_W1 = d_in[18];
    const void* vdwA_b1 = d_in[19];
    const void* vdwA_W2 = d_in[20];
    const void* vdwA_b2 = d_in[21];
    const void* dc_W1 = d_in[22];
    const void* dc_b1 = d_in[23];
    const void* dc_W2 = d_in[24];
    const void* dc_b2 = d_in[25];
    const void* hbond_coeff = d_in[26];
    const void* metal_coeff = d_in[27];
    const void* hydrophobic_coeff = d_in[28];
    const void* rotor_coeff = d_in[29];

    float* ws = (float*)d_ws;
    size_t off = 0;
    float* lig_x = ws + off;  off += (size_t)BB * LL * DIMD;
    float* tgt_x = ws + off;  off += (size_t)BB * TT * DIMD;
    float* h_lig = ws + off;  off += (size_t)BB * LL * DIMD;
    float* h_tgt = ws + off;  off += (size_t)BB * TT * DIMD;
    float* hA_lig = ws + off; off += (size_t)BB * LL * DIMD;
    float* hA_tgt = ws + off; off += (size_t)BB * TT * DIMD;
    float* accum = ws + off;  off += 32;
    int* flagp = (int*)(ws + off); off += 2;
    float* e_buf = ws + off;  off += (size_t)BB * TT * TT;   // 8MB; reused for transposes
    float* part1 = ws + off;  off += (size_t)BB * TT * DIMD; // 2MB split-K partial
    // split-K partial 0 reuses hA buffers (dead after esym_gemm)
    float* part0_lig = hA_lig;
    float* part0_tgt = hA_tgt;
    // pair-MLP projections reuse h/hA buffers (dead after the GAT loop)
    float* ligdc = h_lig;
    float* tgtdc = h_tgt;
    float* ligA = hA_lig;
    float* tgtA = hA_tgt;
    // transposed target projections reuse e_buf (dead after the GAT loop)
    float* tgtdcT = e_buf;
    float* tgtAT  = e_buf + (size_t)BB * DIMD * TT;

    init_ws<<<1, 64, 0, stream>>>((const unsigned int*)emb_W, accum, flagp);

    // embeddings: x = h @ emb_W
    embed_rows<<<BB * LL, DIMD, 0, stream>>>(ligand_h, emb_W, lig_x, 54, flagp);
    embed_rows<<<BB * TT, DIMD, 0, stream>>>(target_h, emb_W, tgt_x, 54, flagp);

    for (int i = 0; i < 3; ++i) {
        long offW = (long)i * DIMD * DIMD;   // element offsets (dtype-agnostic)
        long offWb = (long)i * DIMD;
        long offgW = (long)i * 2 * DIMD;
        long offgb = i;
        // ligand (N=128)
        gemm_rows_ws<<<BB * LL / 4, DIMD, 0, stream>>>(lig_x, gat_W, offW, gat_Wb, offWb, 1, h_lig, flagp);
        gemm_rows_ws<<<BB * LL / 4, DIMD, 0, stream>>>(h_lig, gat_A, offW, nullptr, 0, 0, hA_lig, flagp);
        esym_gemm<<<dim3(LL / BMT, LL / BMT, BB), 256, 0, stream>>>(hA_lig, h_lig, e_buf, LL);
        att_softmax<2><<<dim3(LL / 4, BB), 256, 0, stream>>>(e_buf, ligand_adj, LL, flagp);
        hp_gemm<<<dim3(LL / 32, 2, BB), 256, 0, stream>>>(e_buf, h_lig, part0_lig, part1, LL);
        gat_gate<<<dim3(LL / 4, BB), 256, 0, stream>>>(lig_x, part0_lig, part1,
                                                       gat_gW, offgW, gat_gb, offgb, LL, flagp);
        // target (N=512)
        gemm_rows_ws<<<BB * TT / 4, DIMD, 0, stream>>>(tgt_x, gat_W, offW, gat_Wb, offWb, 1, h_tgt, flagp);
        gemm_rows_ws<<<BB * TT / 4, DIMD, 0, stream>>>(h_tgt, gat_A, offW, nullptr, 0, 0, hA_tgt, flagp);
        esym_gemm<<<dim3(TT / BMT, TT / BMT, BB), 256, 0, stream>>>(hA_tgt, h_tgt, e_buf, TT);
        att_softmax<8><<<dim3(TT / 4, BB), 256, 0, stream>>>(e_buf, target_adj, TT, flagp);
        hp_gemm<<<dim3(TT / 32, 2, BB), 256, 0, stream>>>(e_buf, h_tgt, part0_tgt, part1, TT);
        gat_gate<<<dim3(TT / 4, BB), 256, 0, stream>>>(tgt_x, part0_tgt, part1,
                                                       gat_gW, offgW, gat_gb, offgb, TT, flagp);
    }

    // pair-MLP projections (split W1 == concat math; b1 folded into ligand side)
    gemm_rows_ws<<<BB * LL / 4, DIMD, 0, stream>>>(lig_x, dc_W1, 0, dc_b1, 0, 1, ligdc, flagp);
    gemm_rows_ws<<<BB * TT / 4, DIMD, 0, stream>>>(tgt_x, dc_W1, (long)DIMD * DIMD, nullptr, 0, 0, tgtdc, flagp);
    gemm_rows_ws<<<BB * LL / 4, DIMD, 0, stream>>>(lig_x, vdwA_W1, 0, vdwA_b1, 0, 1, ligA, flagp);
    gemm_rows_ws<<<BB * TT / 4, DIMD, 0, stream>>>(tgt_x, vdwA_W1, (long)DIMD * DIMD, nullptr, 0, 0, tgtA, flagp);

    // transpose target projections for coalesced pair_energy reads
    transpose_to_T<<<dim3(TT / 32, DIMD / 32, BB), 256, 0, stream>>>(tgtdc, tgtdcT, TT);
    transpose_to_T<<<dim3(TT / 32, DIMD / 32, BB), 256, 0, stream>>>(tgtA, tgtAT, TT);

    pair_energy<<<dim3(LL / 2, BB), 256, 0, stream>>>(
        ligdc, tgtdcT, ligA, tgtAT, dc_W2, dc_b2, vdwA_W2, vdwA_b2,
        ligand_pos, target_pos, ligand_vdw, target_vdw,
        ligand_valid, target_valid, interaction_indice, accum, flagp);

    finalize<<<1, 64, 0, stream>>>(accum, hbond_coeff, metal_coeff,
                                   hydrophobic_coeff, rotor_coeff, rotor, d_out, flagp);
}

// Round 4
// 462.097 us; speedup vs baseline: 3.2866x; 1.3188x over previous
//
#include <hip/hip_runtime.h>
#include <hip/hip_bf16.h>
#include <math.h>

typedef __hip_bfloat16 bf16;

#define DIMD 128
#define BB 8
#define LL 128
#define TT 512

// esym tile params
#define BMT 64
#define BKT 32
#define TGT_TILES 36   // 8*9/2 upper-tri tiles (N=512 / 64)
#define LIG_TILES 3    // 2*3/2 upper-tri tiles (N=128 / 64)

// Runtime-dtype load of external inputs: bf==1 -> bf16, else f32.
__device__ __forceinline__ float LD(const void* p, long i, int bf) {
    if (bf) return __bfloat162float(((const bf16*)p)[i]);
    return ((const float*)p)[i];
}

// Detect external dtype from emb_W bit patterns + zero the accumulators.
__global__ void init_ws(const unsigned int* __restrict__ embw_raw,
                        float* __restrict__ accum, int* __restrict__ flagp) {
    int t = threadIdx.x;
    if (t < 32) accum[t] = 0.0f;
    if (t == 0) {
        int cnt = 0;
        for (int k = 0; k < 256; ++k) {
            unsigned int b = (embw_raw[k] >> 8) & 0xffu;
            unsigned int e = b & 0x7fu;
            if (e >= 0x38u && e <= 0x3fu) ++cnt;
        }
        *flagp = (cnt > 128) ? 1 : 0;
    }
}

// Both-sides embedding: rows [0, BB*LL) from Xl, rest from Xt. K=54.
__global__ void embed_both(const void* __restrict__ Xl, const void* __restrict__ Xt,
                           const void* __restrict__ W, float* __restrict__ out,
                           int K, const int* __restrict__ flagp) {
    __shared__ float xrow[DIMD];
    int bf = *flagp;
    int row = blockIdx.x;
    int d = threadIdx.x;
    const void* X; long r;
    if (row < BB * LL) { X = Xl; r = row; }
    else               { X = Xt; r = row - BB * LL; }
    if (d < K) xrow[d] = LD(X, r * K + d, bf);
    __syncthreads();
    float acc = 0.0f;
    for (int k = 0; k < K; ++k)
        acc = fmaf(xrow[k], LD(W, (long)k * DIMD + d, bf), acc);
    out[(long)row * DIMD + d] = acc;
}

// out[row,d] = sum_k X[row,k] * W[off + k*128 + d] (+ bias), dual-sided:
// rows < rowsplit use (offWa, offBa, hasba); rest use (offWb, offBb, hasbb).
// 8 rows/block, 256 threads (2 row-groups x 128 cols).
__global__ void gemm_rows_dual(const float* __restrict__ X, const void* __restrict__ W,
                               long offWa, long offWb, long rowsplit,
                               const void* __restrict__ bias, long offBa, long offBb,
                               int hasba, int hasbb, float* __restrict__ out,
                               const int* __restrict__ flagp) {
    __shared__ float xrow[8][DIMD];
    int bf = *flagp;
    long row0 = (long)blockIdx.x * 8;
    int d = threadIdx.x & 127, rg = threadIdx.x >> 7;
    int sideb = row0 >= rowsplit;
    long offW = sideb ? offWb : offWa;
    long offB = sideb ? offBb : offBa;
    int hasb = sideb ? hasbb : hasba;
#pragma unroll
    for (int r = 0; r < 4; ++r)
        xrow[rg * 4 + r][d] = X[(row0 + rg * 4 + r) * DIMD + d];
    __syncthreads();
    float b0 = hasb ? LD(bias, offB + d, bf) : 0.0f;
    float a0 = b0, a1 = b0, a2 = b0, a3 = b0;
    const float* xr = &xrow[rg * 4][0];
    for (int k = 0; k < DIMD; ++k) {
        float w = LD(W, offW + (long)k * DIMD + d, bf);
        a0 = fmaf(xr[0 * DIMD + k], w, a0);
        a1 = fmaf(xr[1 * DIMD + k], w, a1);
        a2 = fmaf(xr[2 * DIMD + k], w, a2);
        a3 = fmaf(xr[3 * DIMD + k], w, a3);
    }
    long ob = (row0 + rg * 4) * DIMD + d;
    out[ob + 0 * DIMD] = a0;
    out[ob + 1 * DIMD] = a1;
    out[ob + 2 * DIMD] = a2;
    out[ob + 3 * DIMD] = a3;
}

// e[b,j,k] = hA_j . h_k + h_j . hA_k  (symmetric!). Batched GEMM, K=256.
// Upper-triangle tiles only; mirror-write the transpose into the lower tile.
// Grid x: [0,36) target tiles, [36,39) ligand tiles. 64x64 tile, 4x4 acc.
__global__ void esym_both(const float* __restrict__ hA_t, const float* __restrict__ h_t,
                          float* __restrict__ e_t,
                          const float* __restrict__ hA_l, const float* __restrict__ h_l,
                          float* __restrict__ e_l) {
    __shared__ float At[BKT][BMT + 4];
    __shared__ float Bt[BKT][BMT + 4];
    int idx = blockIdx.x, b = blockIdx.y, t = threadIdx.x;
    const float *hA, *h; float* e; int N;
    if (idx < TGT_TILES) { hA = hA_t; h = h_t; e = e_t; N = TT; }
    else { idx -= TGT_TILES; hA = hA_l; h = h_l; e = e_l; N = LL; }
    int jt = (int)((sqrtf(8.0f * idx + 1.0f) - 1.0f) * 0.5f);
    while ((jt + 1) * (jt + 2) / 2 <= idx) ++jt;
    while (jt * (jt + 1) / 2 > idx) --jt;
    int kt = idx - jt * (jt + 1) / 2;   // kt <= jt
    const float* hAb = hA + (long)b * N * DIMD;
    const float* hb  = h  + (long)b * N * DIMD;
    int tm = t & 15, tn = t >> 4;
    int k4 = (t & 7) * 4;
    int row0 = t >> 3;
    float acc[4][4];
#pragma unroll
    for (int i = 0; i < 4; ++i)
#pragma unroll
        for (int jj = 0; jj < 4; ++jj) acc[i][jj] = 0.0f;

#pragma unroll
    for (int c = 0; c < 8; ++c) {
        const float* Ap = (c < 4) ? hAb : hb;
        const float* Bp = (c < 4) ? hb : hAb;
        int ko = (c & 3) * BKT;
        __syncthreads();
#pragma unroll
        for (int rr = 0; rr < 2; ++rr) {
            int row = row0 + rr * 32;
            float4 av = *(const float4*)&Ap[(long)(jt * BMT + row) * DIMD + ko + k4];
            float4 bv = *(const float4*)&Bp[(long)(kt * BMT + row) * DIMD + ko + k4];
            At[k4 + 0][row] = av.x; At[k4 + 1][row] = av.y;
            At[k4 + 2][row] = av.z; At[k4 + 3][row] = av.w;
            Bt[k4 + 0][row] = bv.x; Bt[k4 + 1][row] = bv.y;
            Bt[k4 + 2][row] = bv.z; Bt[k4 + 3][row] = bv.w;
        }
        __syncthreads();
#pragma unroll
        for (int k = 0; k < BKT; ++k) {
            float4 a4 = *(const float4*)&At[k][tm * 4];
            float4 b4 = *(const float4*)&Bt[k][tn * 4];
            float A[4] = {a4.x, a4.y, a4.z, a4.w};
            float Bv[4] = {b4.x, b4.y, b4.z, b4.w};
#pragma unroll
            for (int i = 0; i < 4; ++i)
#pragma unroll
                for (int jj = 0; jj < 4; ++jj)
                    acc[i][jj] = fmaf(A[i], Bv[jj], acc[i][jj]);
        }
    }
    long ebN = (long)b * N;
    long ebase = (ebN + jt * BMT + tm * 4) * N + kt * BMT + tn * 4;
#pragma unroll
    for (int i = 0; i < 4; ++i) {
        float4 v;
        v.x = acc[i][0]; v.y = acc[i][1]; v.z = acc[i][2]; v.w = acc[i][3];
        *(float4*)&e[ebase + (long)i * N] = v;
    }
    if (jt != kt) {   // mirror tile (transpose), also float4-coalesced
        long mbase = (ebN + kt * BMT + tn * 4) * N + jt * BMT + tm * 4;
#pragma unroll
        for (int jj = 0; jj < 4; ++jj) {
            float4 v;
            v.x = acc[0][jj]; v.y = acc[1][jj]; v.z = acc[2][jj]; v.w = acc[3][jj];
            *(float4*)&e[mbase + (long)jj * N] = v;
        }
    }
}

// att row softmax, one WAVE per row (no barriers). In-place on e.
template<int CNT>
__device__ __forceinline__ void softmax_row(float* __restrict__ erow,
                                            const void* __restrict__ adj,
                                            long adjbase, int bf) {
    int lane = threadIdx.x & 63;
    float vals[CNT], av[CNT];
    float m = -3.4e38f;
#pragma unroll
    for (int i = 0; i < CNT; ++i) {
        int k = lane + i * 64;
        float a = LD(adj, adjbase + k, bf);
        float v = (a > 0.0f) ? erow[k] : -9e15f;
        av[i] = a; vals[i] = v;
        m = fmaxf(m, v);
    }
#pragma unroll
    for (int s = 32; s > 0; s >>= 1) m = fmaxf(m, __shfl_xor(m, s));
    float sum = 0.0f;
#pragma unroll
    for (int i = 0; i < CNT; ++i) { vals[i] = expf(vals[i] - m); sum += vals[i]; }
#pragma unroll
    for (int s = 32; s > 0; s >>= 1) sum += __shfl_xor(sum, s);
    float inv = 1.0f / sum;
#pragma unroll
    for (int i = 0; i < CNT; ++i)
        erow[lane + i * 64] = vals[i] * av[i] * inv;
}

// x < TT/4: target rows; else ligand rows. 4 waves = 4 rows per block.
__global__ void att_softmax_both(float* __restrict__ e_t, float* __restrict__ e_l,
                                 const void* __restrict__ adj_t, const void* __restrict__ adj_l,
                                 const int* __restrict__ flagp) {
    int bf = *flagp;
    int b = blockIdx.y, x = blockIdx.x;
    int jr = threadIdx.x >> 6;
    if (x < TT / 4) {
        int j = x * 4 + jr;
        long base = ((long)b * TT + j) * TT;
        softmax_row<8>(e_t + base, adj_t, base, bf);
    } else {
        int j = (x - TT / 4) * 4 + jr;
        long base = ((long)b * LL + j) * LL;
        softmax_row<2>(e_l + base, adj_l, base, bf);
    }
}

// Partial hp GEMM: part[b][j][d] = sum over k-chunk of att[b][j][k]*h[b][k][d]
// BM=32, BN=128, BK=32, 256 threads, 4x4 acc, split-K=2 via blockIdx.y.
// Grid x: [0,16) target row-tiles, [16,20) ligand row-tiles.
__global__ void hp_gemm_both(const float* __restrict__ att_t, const float* __restrict__ h_t,
                             float* __restrict__ p0_t, float* __restrict__ p1_t,
                             const float* __restrict__ att_l, const float* __restrict__ h_l,
                             float* __restrict__ p0_l, float* __restrict__ p1_l) {
    __shared__ float At[32][36];
    __shared__ float Ht[32][DIMD];
    int jt = blockIdx.x, kc = blockIdx.y, b = blockIdx.z;
    int t = threadIdx.x;
    const float *att, *h; float *part0, *part1; int N;
    if (jt < 16) { att = att_t; h = h_t; part0 = p0_t; part1 = p1_t; N = TT; }
    else { jt -= 16; att = att_l; h = h_l; part0 = p0_l; part1 = p1_l; N = LL; }
    const float* attb = att + (long)b * N * N;
    const float* hb = h + (long)b * N * DIMD;
    int tm = t & 7, tn = t >> 3;
    float acc[4][4] = {};
    int kchunk = N / 2;
    int kbeg = kc * kchunk;
    int ar = t >> 3;
    int ac4 = (t & 7) * 4;
    int hk = t >> 5;
    int hc4 = (t & 31) * 4;
    for (int k0 = kbeg; k0 < kbeg + kchunk; k0 += 32) {
        __syncthreads();
        float4 av = *(const float4*)&attb[(long)(jt * 32 + ar) * N + k0 + ac4];
        At[ac4 + 0][ar] = av.x; At[ac4 + 1][ar] = av.y;
        At[ac4 + 2][ar] = av.z; At[ac4 + 3][ar] = av.w;
#pragma unroll
        for (int p = 0; p < 4; ++p)
            *(float4*)&Ht[hk + p * 8][hc4] = *(const float4*)&hb[(long)(k0 + hk + p * 8) * DIMD + hc4];
        __syncthreads();
#pragma unroll
        for (int k = 0; k < 32; ++k) {
            float4 a4 = *(const float4*)&At[k][tm * 4];
            float4 h4 = *(const float4*)&Ht[k][tn * 4];
            float A[4] = {a4.x, a4.y, a4.z, a4.w};
            float H[4] = {h4.x, h4.y, h4.z, h4.w};
#pragma unroll
            for (int i = 0; i < 4; ++i)
#pragma unroll
                for (int jj = 0; jj < 4; ++jj)
                    acc[i][jj] = fmaf(A[i], H[jj], acc[i][jj]);
        }
    }
    float* outp = (kc == 0) ? part0 : part1;
    long obase = ((long)b * N + jt * 32 + tm * 4) * DIMD + tn * 4;
#pragma unroll
    for (int i = 0; i < 4; ++i) {
        float4 v; v.x = acc[i][0]; v.y = acc[i][1]; v.z = acc[i][2]; v.w = acc[i][3];
        *(float4*)&outp[obase + (long)i * DIMD] = v;
    }
}

// Gate: hp = relu(part0+part1); coeff = sigmoid(concat(x,hp)@gW+gb); x updated.
// One WAVE per row; x < TT/4 -> target rows, else ligand.
__global__ void gat_gate_both(float* __restrict__ x_t, float* __restrict__ x_l,
                              const float* __restrict__ p0_t, const float* __restrict__ p1_t,
                              const float* __restrict__ p0_l, const float* __restrict__ p1_l,
                              const void* __restrict__ gW, long offgW,
                              const void* __restrict__ gb, long offgb,
                              const int* __restrict__ flagp) {
    int bf = *flagp;
    int b = blockIdx.y, x = blockIdx.x;
    int jr = threadIdx.x >> 6, lane = threadIdx.x & 63;
    float* xb; const float *part0, *part1; long rbase;
    if (x < TT / 4) {
        int j = x * 4 + jr;
        rbase = ((long)b * TT + j) * DIMD;
        xb = x_t; part0 = p0_t; part1 = p1_t;
    } else {
        int j = (x - TT / 4) * 4 + jr;
        rbase = ((long)b * LL + j) * DIMD;
        xb = x_l; part0 = p0_l; part1 = p1_l;
    }
    float* xrow = xb + rbase;
    float hp0 = fmaxf(part0[rbase + lane] + part1[rbase + lane], 0.0f);
    float hp1 = fmaxf(part0[rbase + lane + 64] + part1[rbase + lane + 64], 0.0f);
    float x0 = xrow[lane], x1 = xrow[lane + 64];
    float g = x0 * LD(gW, offgW + lane, bf) + x1 * LD(gW, offgW + lane + 64, bf)
            + hp0 * LD(gW, offgW + DIMD + lane, bf) + hp1 * LD(gW, offgW + DIMD + lane + 64, bf);
#pragma unroll
    for (int s = 32; s > 0; s >>= 1) g += __shfl_xor(g, s);
    g += LD(gb, offgb, bf);
    float coeff = 1.0f / (1.0f + expf(-g));
    xrow[lane] = coeff * x0 + (1.0f - coeff) * hp0;
    xrow[lane + 64] = coeff * x1 + (1.0f - coeff) * hp1;
}

// Both transposes in one launch: z<BB -> (in0->out0, b=z), else (in1->out1).
__global__ void transpose_both(const float* __restrict__ in0, float* __restrict__ out0,
                               const float* __restrict__ in1, float* __restrict__ out1) {
    __shared__ float tile[32][33];
    int z = blockIdx.z;
    const float* in; float* outT; int b;
    if (z < BB) { in = in0; outT = out0; b = z; }
    else        { in = in1; outT = out1; b = z - BB; }
    int n0 = blockIdx.x * 32;
    int d0 = blockIdx.y * 32;
    int t = threadIdx.x;
    int tx = t & 31, ty = t >> 5;
    for (int r = ty; r < 32; r += 8)
        tile[r][tx] = in[((long)b * TT + n0 + r) * DIMD + d0 + tx];
    __syncthreads();
    for (int r = ty; r < 32; r += 8)
        outT[((long)b * DIMD + d0 + r) * TT + n0 + tx] = tile[tx][r];
}

// Pair energies. Block = (b, 2 ligand rows). Lane handles tt = 2t, 2t+1.
__global__ void pair_energy(const float* __restrict__ ligdc, const float* __restrict__ tgtdcT,
                            const float* __restrict__ ligA, const float* __restrict__ tgtAT,
                            const void* __restrict__ dcW2, const void* __restrict__ dcb2,
                            const void* __restrict__ AW2, const void* __restrict__ Ab2,
                            const void* __restrict__ lpos, const void* __restrict__ tpos,
                            const void* __restrict__ lrad, const void* __restrict__ trad,
                            const void* __restrict__ lval, const void* __restrict__ tval,
                            const void* __restrict__ ii, float* __restrict__ accum,
                            const int* __restrict__ flagp) {
    int bf = *flagp;
    int l0 = blockIdx.x * 2, b = blockIdx.y, t = threadIdx.x;
    __shared__ __align__(16) float sdc0[DIMD], sdc1[DIMD], sA0[DIMD], sA1[DIMD];
    __shared__ __align__(16) float w2dc[DIMD], w2A[DIMD];
    __shared__ float red[256];
    if (t < DIMD) {
        sdc0[t] = ligdc[((long)b * LL + l0) * DIMD + t];
        sA0[t]  = ligA [((long)b * LL + l0) * DIMD + t];
        w2dc[t] = LD(dcW2, t, bf);
        w2A[t]  = LD(AW2, t, bf);
    } else {
        int u = t - DIMD;
        sdc1[u] = ligdc[((long)b * LL + l0 + 1) * DIMD + u];
        sA1[u]  = ligA [((long)b * LL + l0 + 1) * DIMD + u];
    }
    __syncthreads();
    int tt0 = t * 2;
    const float* tdT = tgtdcT + (long)b * DIMD * TT;
    const float* taT = tgtAT  + (long)b * DIMD * TT;
    float adc00 = 0.0f, adc01 = 0.0f, adc10 = 0.0f, adc11 = 0.0f;
    float aA00 = 0.0f, aA01 = 0.0f, aA10 = 0.0f, aA11 = 0.0f;
    for (int i4 = 0; i4 < DIMD; i4 += 4) {
        float4 wd = *(const float4*)&w2dc[i4];
        float4 wa = *(const float4*)&w2A[i4];
        float4 v0d = *(const float4*)&sdc0[i4];
        float4 v1d = *(const float4*)&sdc1[i4];
        float4 v0a = *(const float4*)&sA0[i4];
        float4 v1a = *(const float4*)&sA1[i4];
        float wdv[4] = {wd.x, wd.y, wd.z, wd.w};
        float wav[4] = {wa.x, wa.y, wa.z, wa.w};
        float s0d[4] = {v0d.x, v0d.y, v0d.z, v0d.w};
        float s1d[4] = {v1d.x, v1d.y, v1d.z, v1d.w};
        float s0a[4] = {v0a.x, v0a.y, v0a.z, v0a.w};
        float s1a[4] = {v1a.x, v1a.y, v1a.z, v1a.w};
#pragma unroll
        for (int j = 0; j < 4; ++j) {
            float2 td = *(const float2*)&tdT[(long)(i4 + j) * TT + tt0];
            float2 ta = *(const float2*)&taT[(long)(i4 + j) * TT + tt0];
            adc00 = fmaf(fmaxf(td.x + s0d[j], 0.0f), wdv[j], adc00);
            adc01 = fmaf(fmaxf(td.y + s0d[j], 0.0f), wdv[j], adc01);
            adc10 = fmaf(fmaxf(td.x + s1d[j], 0.0f), wdv[j], adc10);
            adc11 = fmaf(fmaxf(td.y + s1d[j], 0.0f), wdv[j], adc11);
            aA00 = fmaf(fmaxf(ta.x + s0a[j], 0.0f), wav[j], aA00);
            aA01 = fmaf(fmaxf(ta.y + s0a[j], 0.0f), wav[j], aA01);
            aA10 = fmaf(fmaxf(ta.x + s1a[j], 0.0f), wav[j], aA10);
            aA11 = fmaf(fmaxf(ta.y + s1a[j], 0.0f), wav[j], aA11);
        }
    }
    float lx0 = LD(lpos, ((long)b * LL + l0) * 3 + 0, bf);
    float ly0 = LD(lpos, ((long)b * LL + l0) * 3 + 1, bf);
    float lz0 = LD(lpos, ((long)b * LL + l0) * 3 + 2, bf);
    float lx1 = LD(lpos, ((long)b * LL + l0 + 1) * 3 + 0, bf);
    float ly1 = LD(lpos, ((long)b * LL + l0 + 1) * 3 + 1, bf);
    float lz1 = LD(lpos, ((long)b * LL + l0 + 1) * 3 + 2, bf);
    float lr0 = LD(lrad, (long)b * LL + l0, bf);
    float lr1 = LD(lrad, (long)b * LL + l0 + 1, bf);
    float lv0 = LD(lval, (long)b * LL + l0, bf);
    float lv1 = LD(lval, (long)b * LL + l0 + 1, bf);
    float cdcb2 = LD(dcb2, 0, bf), cab2 = LD(Ab2, 0, bf);
    long iiA0 = ((long)(b * 3 + 0) * LL + l0) * TT;
    long iiB0 = ((long)(b * 3 + 1) * LL + l0) * TT;
    long iiC0 = ((long)(b * 3 + 2) * LL + l0) * TT;
    long iiA1 = iiA0 + TT, iiB1 = iiB0 + TT, iiC1 = iiC0 + TT;
    float p0 = 0.0f, p1 = 0.0f, p2 = 0.0f, p3 = 0.0f;
#pragma unroll
    for (int jj = 0; jj < 2; ++jj) {
        int tt = tt0 + jj;
        float tx = LD(tpos, ((long)b * TT + tt) * 3 + 0, bf);
        float ty = LD(tpos, ((long)b * TT + tt) * 3 + 1, bf);
        float tz = LD(tpos, ((long)b * TT + tt) * 3 + 2, bf);
        float tr = LD(trad, (long)b * TT + tt, bf);
        float tv = LD(tval, (long)b * TT + tt, bf);
#pragma unroll
        for (int li = 0; li < 2; ++li) {
            float dx = (li ? lx1 : lx0) - tx;
            float dy = (li ? ly1 : ly0) - ty;
            float dz = (li ? lz1 : lz0) - tz;
            float dm = sqrtf(dx * dx + dy * dy + dz * dz + 1e-10f);
            if (dm < 0.5f) dm = 1e10f;
            float adcv = jj ? (li ? adc11 : adc01) : (li ? adc10 : adc00);
            float aAv  = jj ? (li ? aA11  : aA01)  : (li ? aA10  : aA00);
            float dev = tanhf(adcv + cdcb2) * 0.2f;
            float vdws = (li ? lr1 : lr0) + tr + dev;
            float dm0 = (vdws < 1e-4f) ? 1.0f : vdws;
            float ratio = dm0 / dm;
            float r2 = ratio * ratio, r6 = r2 * r2 * r2, r12 = r6 * r6;
            float en = fminf(r12 - 2.0f * r6, 100.0f) * (li ? lv1 : lv0) * tv;
            float As = 1.0f / (1.0f + expf(-(aAv + cab2)));
            As = As * (0.0356f - 0.0178f) + 0.0178f;
            p0 = fmaf(As, en, p0);
            float dd = dm - vdws;
            float ramp = fminf(fmaxf(dd * (1.0f / -0.7f), 0.0f), 1.0f);
            p1 = fmaf(ramp, LD(ii, (li ? iiA1 : iiA0) + tt, bf), p1);
            p2 = fmaf(ramp, LD(ii, (li ? iiB1 : iiB0) + tt, bf), p2);
            float ramp2 = fminf(fmaxf(-dd + 1.5f, 0.0f), 1.0f);
            p3 = fmaf(ramp2, LD(ii, (li ? iiC1 : iiC0) + tt, bf), p3);
        }
    }
    for (int e = 0; e < 4; ++e) {
        float v = (e == 0) ? p0 : (e == 1) ? p1 : (e == 2) ? p2 : p3;
        red[t] = v; __syncthreads();
        for (int s = 128; s > 0; s >>= 1) { if (t < s) red[t] += red[t + s]; __syncthreads(); }
        if (t == 0) atomicAdd(&accum[b * 4 + e], red[0]);
        __syncthreads();
    }
}

__global__ void finalize(const float* __restrict__ accum, const void* __restrict__ hb,
                         const void* __restrict__ mc, const void* __restrict__ hyd,
                         const void* __restrict__ rc, const void* __restrict__ rotor,
                         void* __restrict__ out, const int* __restrict__ flagp) {
    int bf = *flagp;
    int t = threadIdx.x;  // 64 threads, use first 32
    if (t >= 32) return;
    int b = t >> 2, e = t & 3;
    float v = accum[t];
    if (e == 1) { float c = LD(hb, 0, bf);  v = -c * c * v; }
    else if (e == 2) { float c = LD(mc, 0, bf);  v = -c * c * v; }
    else if (e == 3) { float c = LD(hyd, 0, bf); v = -c * c * v; }
    float r = LD(rc, 0, bf);
    float den = 1.0f + r * r * LD(rotor, b, bf);
    float res = v / den;
    if (bf) ((bf16*)out)[t] = __float2bfloat16(res);
    else    ((float*)out)[t] = res;
}

extern "C" void kernel_launch(void* const* d_in, const int* in_sizes, int n_in,
                              void* d_out, int out_size, void* d_ws, size_t ws_size,
                              hipStream_t stream) {
    const void* ligand_h = d_in[0];
    const void* target_h = d_in[1];
    const void* ligand_adj = d_in[2];
    const void* target_adj = d_in[3];
    const void* interaction_indice = d_in[4];
    const void* ligand_pos = d_in[5];
    const void* target_pos = d_in[6];
    const void* rotor = d_in[7];
    const void* ligand_vdw = d_in[8];
    const void* target_vdw = d_in[9];
    const void* ligand_valid = d_in[10];
    const void* target_valid = d_in[11];
    const void* emb_W = d_in[12];
    const void* gat_W = d_in[13];
    const void* gat_Wb = d_in[14];
    const void* gat_A = d_in[15];
    const void* gat_gW = d_in[16];
    const void* gat_gb = d_in[17];
    const void* vdwA_W1 = d_in[18];
    const void* vdwA_b1 = d_in[19];
    const void* vdwA_W2 = d_in[20];
    const void* vdwA_b2 = d_in[21];
    const void* dc_W1 = d_in[22];
    const void* dc_b1 = d_in[23];
    const void* dc_W2 = d_in[24];
    const void* dc_b2 = d_in[25];
    const void* hbond_coeff = d_in[26];
    const void* metal_coeff = d_in[27];
    const void* hydrophobic_coeff = d_in[28];
    const void* rotor_coeff = d_in[29];

    float* ws = (float*)d_ws;
    size_t off = 0;
    float* lig_x = ws + off;  off += (size_t)BB * LL * DIMD;   // contiguous with tgt_x
    float* tgt_x = ws + off;  off += (size_t)BB * TT * DIMD;
    float* h_lig = ws + off;  off += (size_t)BB * LL * DIMD;   // contiguous with h_tgt
    float* h_tgt = ws + off;  off += (size_t)BB * TT * DIMD;
    float* hA_lig = ws + off; off += (size_t)BB * LL * DIMD;   // contiguous with hA_tgt
    float* hA_tgt = ws + off; off += (size_t)BB * TT * DIMD;
    float* accum = ws + off;  off += 32;
    int* flagp = (int*)(ws + off); off += 2;
    float* e_buf = ws + off;  off += (size_t)BB * TT * TT;     // 8MB target e; reused for transposes
    float* e_lig = ws + off;  off += (size_t)BB * LL * LL;     // 512KB ligand e
    float* part1 = ws + off;  off += (size_t)BB * (TT + LL) * DIMD; // split-K partials
    float* part1_t = part1;
    float* part1_l = part1 + (size_t)BB * TT * DIMD;
    // split-K partial 0 reuses hA buffers (dead after esym)
    float* part0_lig = hA_lig;
    float* part0_tgt = hA_tgt;
    // pair-MLP projections reuse h/hA buffers (dead after the GAT loop)
    float* ligdc = h_lig;    // merged out base = h_lig (rows: lig then tgt)
    float* ligA = hA_lig;
    // transposed target projections reuse e_buf (dead after the GAT loop)
    float* tgtdcT = e_buf;
    float* tgtAT  = e_buf + (size_t)BB * DIMD * TT;
    float* tgtdc = h_tgt;
    float* tgtA  = hA_tgt;

    init_ws<<<1, 64, 0, stream>>>((const unsigned int*)emb_W, accum, flagp);

    // embeddings: x = h @ emb_W (both sides, one launch; out rows contiguous)
    embed_both<<<BB * (LL + TT), DIMD, 0, stream>>>(ligand_h, target_h, emb_W, lig_x, 54, flagp);

    const long ROWSPLIT = (long)BB * LL;   // multiple of 8
    for (int i = 0; i < 3; ++i) {
        long offW = (long)i * DIMD * DIMD;
        long offWb = (long)i * DIMD;
        long offgW = (long)i * 2 * DIMD;
        long offgb = i;
        // h = x @ W + Wb ; hA = h @ A    (both sides in one launch each)
        gemm_rows_dual<<<BB * (LL + TT) / 8, 256, 0, stream>>>(
            lig_x, gat_W, offW, offW, ROWSPLIT, gat_Wb, offWb, offWb, 1, 1, h_lig, flagp);
        gemm_rows_dual<<<BB * (LL + TT) / 8, 256, 0, stream>>>(
            h_lig, gat_A, offW, offW, ROWSPLIT, nullptr, 0, 0, 0, 0, hA_lig, flagp);
        // e (symmetric, upper tiles + mirror), both sides
        esym_both<<<dim3(TGT_TILES + LIG_TILES, BB), 256, 0, stream>>>(
            hA_tgt, h_tgt, e_buf, hA_lig, h_lig, e_lig);
        att_softmax_both<<<dim3(TT / 4 + LL / 4, BB), 256, 0, stream>>>(
            e_buf, e_lig, target_adj, ligand_adj, flagp);
        hp_gemm_both<<<dim3(20, 2, BB), 256, 0, stream>>>(
            e_buf, h_tgt, part0_tgt, part1_t, e_lig, h_lig, part0_lig, part1_l);
        gat_gate_both<<<dim3(TT / 4 + LL / 4, BB), 256, 0, stream>>>(
            tgt_x, lig_x, part0_tgt, part1_t, part0_lig, part1_l,
            gat_gW, offgW, gat_gb, offgb, flagp);
    }

    // pair-MLP projections: lig rows use W1[:D] (+b1), tgt rows use W1[D:]
    gemm_rows_dual<<<BB * (LL + TT) / 8, 256, 0, stream>>>(
        lig_x, dc_W1, 0, (long)DIMD * DIMD, ROWSPLIT, dc_b1, 0, 0, 1, 0, ligdc, flagp);
    gemm_rows_dual<<<BB * (LL + TT) / 8, 256, 0, stream>>>(
        lig_x, vdwA_W1, 0, (long)DIMD * DIMD, ROWSPLIT, vdwA_b1, 0, 0, 1, 0, ligA, flagp);

    // transpose target projections for coalesced pair_energy reads (one launch)
    transpose_both<<<dim3(TT / 32, DIMD / 32, 2 * BB), 256, 0, stream>>>(
        tgtdc, tgtdcT, tgtA, tgtAT);

    pair_energy<<<dim3(LL / 2, BB), 256, 0, stream>>>(
        ligdc, tgtdcT, ligA, tgtAT, dc_W2, dc_b2, vdwA_W2, vdwA_b2,
        ligand_pos, target_pos, ligand_vdw, target_vdw,
        ligand_valid, target_valid, interaction_indice, accum, flagp);

    finalize<<<1, 64, 0, stream>>>(accum, hbond_coeff, metal_coeff,
                                   hydrophobic_coeff, rotor_coeff, rotor, d_out, flagp);
}